// Round 2
// baseline (1475.186 us; speedup 1.0000x reference)
//
#include <hip/hip_runtime.h>
#include <hip/hip_bf16.h>

#define DEVFN __device__ __forceinline__

// ---- dual-dtype helpers: flags[0]=1 -> floats are f32 (else bf16);
//                          flags[1]=1 -> ints are int64 (else int32)
DEVFN float ldf(const void* p, size_t i, bool f32) {
    return f32 ? ((const float*)p)[i]
               : __bfloat162float(((const __hip_bfloat16*)p)[i]);
}
DEVFN int ldidx(const void* p, size_t i, bool i64) {
    return i64 ? (int)((const long long*)p)[i] : ((const int*)p)[i];
}
DEVFN void stf(void* p, size_t i, float v, bool f32) {
    if (f32) ((float*)p)[i] = v;
    else     ((__hip_bfloat16*)p)[i] = __float2bfloat16(v);
}

// monotonic float<->uint encoding for atomicMax-based segment max
DEVFN unsigned enc_f(float f) {
    unsigned b = __float_as_uint(f);
    return (b & 0x80000000u) ? ~b : (b | 0x80000000u);
}
DEVFN float dec_f(unsigned u) {
    return (u & 0x80000000u) ? __uint_as_float(u ^ 0x80000000u) : __uint_as_float(~u);
}

__global__ void detect_k(const void* x, const void* ei, int* flags) {
    if (threadIdx.x == 0 && blockIdx.x == 0) {
        // float dtype: bf16 interpretation of real bf16 data is always sane;
        // of f32 data it yields many huge/NaN values.
        const __hip_bfloat16* xb = (const __hip_bfloat16*)x;
        int bad = 0;
        for (int i = 0; i < 512; ++i) {
            float v = __bfloat162float(xb[i]);
            if (!(v == v) || fabsf(v) > 1.0e6f) bad++;
        }
        flags[0] = (bad > 16) ? 1 : 0;
        // int dtype: node ids < 2^16, so int64 high words are all zero.
        const unsigned* w = (const unsigned*)ei;
        int zeros = 0;
        for (int i = 0; i < 64; ++i) if (w[2 * i + 1] == 0u) zeros++;
        flags[1] = (zeros >= 60) ? 1 : 0;
    }
}

__global__ void zero_f32(float* __restrict__ p, long n) {
    long i = (long)blockIdx.x * blockDim.x + threadIdx.x;
    long st = (long)gridDim.x * blockDim.x;
    for (; i < n; i += st) p[i] = 0.f;
}

// h = x @ W (per-node), fused with alpha_src/alpha_dst per-node dot products.
// XEXT: input comes from d_in (dtype per flags); else internal f32 workspace.
template <bool XEXT, int FIN, int FOUT, int HEADS>
__global__ __launch_bounds__(128) void gemm_alpha_k(
    const void* __restrict__ xin, const void* __restrict__ Wv,
    const void* __restrict__ asv, const void* __restrict__ adv,
    float* __restrict__ h_out, float* __restrict__ as_out, float* __restrict__ ad_out,
    int N, const int* __restrict__ flags)
{
    const bool f32 = flags[0] != 0;
    constexpr int NPB = 128 / FOUT;  // nodes per block
    __shared__ float xs[NPB][FIN];
    __shared__ float red[4];
    const int tid = threadIdx.x;
    const int node0 = blockIdx.x * NPB;

    for (int i = tid; i < NPB * FIN; i += 128) {
        int nl = i / FIN, k = i - nl * FIN;
        int n = node0 + nl;
        float v = 0.f;
        if (n < N) {
            size_t gi = (size_t)n * FIN + k;
            v = XEXT ? ldf(xin, gi, f32) : ((const float*)xin)[gi];
        }
        xs[nl][k] = v;
    }
    __syncthreads();

    const int nl = tid / FOUT;
    const int col = tid - nl * FOUT;
    const int n = node0 + nl;

    float acc = 0.f;
#pragma unroll 8
    for (int k = 0; k < FIN; ++k)
        acc = fmaf(xs[nl][k], ldf(Wv, (size_t)k * FOUT + col, f32), acc);

    if (n < N) h_out[(size_t)n * FOUT + col] = acc;

    float cs = acc * ldf(asv, col, f32);
    float cd = acc * ldf(adv, col, f32);

    if constexpr (FOUT == 128 && HEADS == 2) {
        for (int o = 32; o; o >>= 1) { cs += __shfl_down(cs, o); cd += __shfl_down(cd, o); }
        int w = tid >> 6;
        if ((tid & 63) == 0 && n < N) {
            as_out[(size_t)n * 2 + w] = cs;
            ad_out[(size_t)n * 2 + w] = cd;
        }
    } else if constexpr (FOUT == 128 && HEADS == 1) {
        for (int o = 32; o; o >>= 1) { cs += __shfl_down(cs, o); cd += __shfl_down(cd, o); }
        if ((tid & 63) == 0) { red[(tid >> 6)] = cs; red[2 + (tid >> 6)] = cd; }
        __syncthreads();
        if (tid == 0 && n < N) {
            as_out[n] = red[0] + red[1];
            ad_out[n] = red[2] + red[3];
        }
    } else {
        for (int o = 8; o; o >>= 1) { cs += __shfl_down(cs, o, 16); cd += __shfl_down(cd, o, 16); }
        if (col == 0 && n < N) { as_out[n] = cs; ad_out[n] = cd; }
    }
}

template <int HEADS>
__global__ void edge_logits_k(const float* __restrict__ as_, const float* __restrict__ ad_,
                              const void* __restrict__ ei, float* __restrict__ logits,
                              unsigned* __restrict__ m_enc, int E, const int* __restrict__ flags)
{
    const bool i64 = flags[1] != 0;
    int idx = blockIdx.x * blockDim.x + threadIdx.x;
    if (idx >= E * HEADS) return;
    int e = idx / HEADS, h = idx - (idx / HEADS) * HEADS;
    int s_ = ldidx(ei, e, i64);
    int d_ = ldidx(ei, (size_t)E + e, i64);
    float lg = as_[(size_t)s_ * HEADS + h] + ad_[(size_t)d_ * HEADS + h];
    lg = lg > 0.f ? lg : 0.2f * lg;  // leaky_relu 0.2
    logits[idx] = lg;
    atomicMax(&m_enc[(size_t)d_ * HEADS + h], enc_f(lg));
}

template <int HEADS>
__global__ void edge_exp_k(float* __restrict__ ev, const unsigned* __restrict__ m_enc,
                           const void* __restrict__ ei, float* __restrict__ s_sum,
                           int E, const int* __restrict__ flags)
{
    const bool i64 = flags[1] != 0;
    int idx = blockIdx.x * blockDim.x + threadIdx.x;
    if (idx >= E * HEADS) return;
    int e = idx / HEADS, h = idx - (idx / HEADS) * HEADS;
    int d_ = ldidx(ei, (size_t)E + e, i64);
    float m = dec_f(m_enc[(size_t)d_ * HEADS + h]);
    float x = expf(ev[idx] - m);
    ev[idx] = x;
    atomicAdd(&s_sum[(size_t)d_ * HEADS + h], x);
}

template <int HEADS>
__global__ void edge_alpha_k(const float* __restrict__ ev, const float* __restrict__ s_sum,
                             const void* __restrict__ ei, void* __restrict__ dout,
                             size_t aoff, int E, const int* __restrict__ flags)
{
    const bool f32 = flags[0] != 0;
    const bool i64 = flags[1] != 0;
    int idx = blockIdx.x * blockDim.x + threadIdx.x;
    if (idx >= E * HEADS) return;
    int e = idx / HEADS, h = idx - (idx / HEADS) * HEADS;
    int d_ = ldidx(ei, (size_t)E + e, i64);
    float a = ev[idx] / (s_sum[(size_t)d_ * HEADS + h] + 1e-16f);
    stf(dout, aoff + idx, a, f32);
}

template <int FOUT, int HEADS>
__global__ void edge_scatter_k(const float* __restrict__ h_t, const float* __restrict__ ev,
                               const float* __restrict__ s_sum, const void* __restrict__ ei,
                               float* __restrict__ acc, int E, const int* __restrict__ flags)
{
    const bool i64 = flags[1] != 0;
    constexpr int C = FOUT / HEADS;
    long idx = (long)blockIdx.x * blockDim.x + threadIdx.x;
    if (idx >= (long)E * FOUT) return;
    int e = (int)(idx / FOUT);
    int col = (int)(idx & (FOUT - 1));
    int h = col / C;
    int s_ = ldidx(ei, e, i64);
    int d_ = ldidx(ei, (size_t)E + e, i64);
    float alpha = ev[(size_t)e * HEADS + h] / (s_sum[(size_t)d_ * HEADS + h] + 1e-16f);
    atomicAdd(&acc[(size_t)d_ * FOUT + col], h_t[(size_t)s_ * FOUT + col] * alpha);
}

template <int FOUT, bool RELU>
__global__ void finalize_k(float* __restrict__ acc, const void* __restrict__ bias,
                           int N, const int* __restrict__ flags)
{
    const bool f32 = flags[0] != 0;
    long idx = (long)blockIdx.x * blockDim.x + threadIdx.x;
    if (idx >= (long)N * FOUT) return;
    int col = (int)(idx & (FOUT - 1));
    float v = acc[idx] + ldf(bias, col, f32);
    if (RELU) v = fmaxf(v, 0.f);
    acc[idx] = v;
}

// layer3 finalize: emb = acc + b3, write emb to d_out, pool per-graph sums
__global__ __launch_bounds__(256) void finalize3_k(
    const float* __restrict__ acc, const void* __restrict__ bias,
    const void* __restrict__ batch, void* __restrict__ dout, size_t emb_off,
    float* __restrict__ g_sum, int N, const int* __restrict__ flags)
{
    const bool f32 = flags[0] != 0;
    const bool i64 = flags[1] != 0;
    __shared__ float gp[256];
    int tid = threadIdx.x;
    gp[tid] = 0.f;
    __syncthreads();
    long idx = (long)blockIdx.x * 256 + tid;
    if (idx < (long)N * 16) {
        int n = (int)(idx >> 4), col = (int)(idx & 15);
        float v = acc[idx] + ldf(bias, col, f32);
        stf(dout, emb_off + idx, v, f32);
        int g = ldidx(batch, n, i64);
        atomicAdd(&gp[g * 16 + col], v);
    }
    __syncthreads();
    float pv = gp[tid];
    if (pv != 0.f) atomicAdd(&g_sum[tid], pv);
}

__global__ __launch_bounds__(256) void head_k(
    const float* __restrict__ g_sum, const void* __restrict__ batch,
    const void* __restrict__ Wl, const void* __restrict__ bl,
    void* __restrict__ dout, size_t gemb_off, int N, const int* __restrict__ flags)
{
    const bool f32 = flags[0] != 0;
    const bool i64 = flags[1] != 0;
    __shared__ float ge[256];
    __shared__ int cnts[16];
    int tid = threadIdx.x;
    if (tid < 16) {
        int lo = 0, hi = N;
        while (lo < hi) { int mid = (lo + hi) >> 1; if (ldidx(batch, mid, i64) < tid) lo = mid + 1; else hi = mid; }
        int l2 = 0, h2 = N;
        while (l2 < h2) { int mid = (l2 + h2) >> 1; if (ldidx(batch, mid, i64) <= tid) l2 = mid + 1; else h2 = mid; }
        cnts[tid] = l2 - lo;
    }
    __syncthreads();
    {
        int g = tid >> 4;
        float v = g_sum[tid] / fmaxf((float)cnts[g], 1.f);
        ge[tid] = v;
        stf(dout, gemb_off + tid, v, f32);
    }
    __syncthreads();
    if (tid < 32) {
        int g = tid >> 1, j = tid & 1;
        float s = ldf(bl, j, f32);
        for (int c = 0; c < 16; ++c) s += ge[g * 16 + c] * ldf(Wl, (size_t)c * 2 + j, f32);
        stf(dout, (size_t)g * 2 + j, s, f32);
    }
}

static inline int cdiv(long a, int b) { return (int)((a + b - 1) / b); }

extern "C" void kernel_launch(void* const* d_in, const int* in_sizes, int n_in,
                              void* d_out, int out_size, void* d_ws, size_t ws_size,
                              hipStream_t stream)
{
    const void* x   = d_in[0];
    const void* ei  = d_in[1];
    const void* batch = d_in[2];
    const void* W1  = d_in[3];
    const void* as1 = d_in[4];
    const void* ad1 = d_in[5];
    const void* b1  = d_in[6];
    const void* W2  = d_in[7];
    const void* as2 = d_in[8];
    const void* ad2 = d_in[9];
    const void* b2  = d_in[10];
    const void* W3  = d_in[11];
    const void* as3 = d_in[12];
    const void* ad3 = d_in[13];
    const void* b3  = d_in[14];
    const void* Wl  = d_in[15];
    const void* bl  = d_in[16];

    const int N = in_sizes[0] / 128;
    const int E = in_sizes[1] / 2;

    int* flags = (int*)d_ws;
    float* ws = (float*)d_ws + 16;
    size_t o = 0;
    float* bufA = ws + o; o += (size_t)N * 128;   // h_t for layers 1,2; layer3 bufs alias it
    float* bufB = ws + o; o += (size_t)N * 128;   // acc / next-layer input
    float* bufD = bufA;                           // layer3 h_t (bufA dead by then)
    float* bufE = bufA + (size_t)N * 16;          // layer3 acc
    float* as_  = ws + o; o += (size_t)N * 2;
    float* ad_  = ws + o; o += (size_t)N * 2;
    unsigned* m_enc = (unsigned*)(ws + o); o += (size_t)N * 2;
    float* s_sum = ws + o; o += (size_t)N * 2;
    float* ev   = ws + o; o += (size_t)E * 2;
    float* g_sum = ws + o; o += 256;

    // output element offsets (dtype-agnostic)
    const size_t off_head = 0;
    const size_t off_gemb = 32;
    const size_t off_emb  = 32 + 256;
    const size_t off_a1   = off_emb + (size_t)N * 16;
    const size_t off_a2   = off_a1 + (size_t)E * 2;
    const size_t off_a3   = off_a2 + (size_t)E;
    (void)off_head;

    const int B = 256;

    detect_k<<<1, 64, 0, stream>>>(x, ei, flags);

    // ---------------- Layer 1: 128 -> (2 heads x 64), concat, relu ----------------
    gemm_alpha_k<true, 128, 128, 2><<<N, 128, 0, stream>>>(x, W1, as1, ad1, bufA, as_, ad_, N, flags);
    zero_f32<<<cdiv((long)N * 2, B), B, 0, stream>>>((float*)m_enc, (long)N * 2);
    zero_f32<<<cdiv((long)N * 2, B), B, 0, stream>>>(s_sum, (long)N * 2);
    zero_f32<<<2048, B, 0, stream>>>(bufB, (long)N * 128);
    edge_logits_k<2><<<cdiv((long)E * 2, B), B, 0, stream>>>(as_, ad_, ei, ev, m_enc, E, flags);
    edge_exp_k<2><<<cdiv((long)E * 2, B), B, 0, stream>>>(ev, m_enc, ei, s_sum, E, flags);
    edge_alpha_k<2><<<cdiv((long)E * 2, B), B, 0, stream>>>(ev, s_sum, ei, d_out, off_a1, E, flags);
    edge_scatter_k<128, 2><<<cdiv((long)E * 128, B), B, 0, stream>>>(bufA, ev, s_sum, ei, bufB, E, flags);
    finalize_k<128, true><<<cdiv((long)N * 128, B), B, 0, stream>>>(bufB, b1, N, flags);

    // ---------------- Layer 2: 128 -> 128, 1 head, mean(=identity), relu ----------------
    gemm_alpha_k<false, 128, 128, 1><<<N, 128, 0, stream>>>(bufB, W2, as2, ad2, bufA, as_, ad_, N, flags);
    zero_f32<<<cdiv((long)N, B), B, 0, stream>>>((float*)m_enc, (long)N);
    zero_f32<<<cdiv((long)N, B), B, 0, stream>>>(s_sum, (long)N);
    zero_f32<<<2048, B, 0, stream>>>(bufB, (long)N * 128);
    edge_logits_k<1><<<cdiv((long)E, B), B, 0, stream>>>(as_, ad_, ei, ev, m_enc, E, flags);
    edge_exp_k<1><<<cdiv((long)E, B), B, 0, stream>>>(ev, m_enc, ei, s_sum, E, flags);
    edge_alpha_k<1><<<cdiv((long)E, B), B, 0, stream>>>(ev, s_sum, ei, d_out, off_a2, E, flags);
    edge_scatter_k<128, 1><<<cdiv((long)E * 128, B), B, 0, stream>>>(bufA, ev, s_sum, ei, bufB, E, flags);
    finalize_k<128, true><<<cdiv((long)N * 128, B), B, 0, stream>>>(bufB, b2, N, flags);

    // ---------------- Layer 3: 128 -> 16, 1 head, mean(=identity), no relu ----------------
    gemm_alpha_k<false, 128, 16, 1><<<cdiv(N, 8), 128, 0, stream>>>(bufB, W3, as3, ad3, bufD, as_, ad_, N, flags);
    zero_f32<<<cdiv((long)N, B), B, 0, stream>>>((float*)m_enc, (long)N);
    zero_f32<<<cdiv((long)N, B), B, 0, stream>>>(s_sum, (long)N);
    zero_f32<<<cdiv((long)N * 16, B), B, 0, stream>>>(bufE, (long)N * 16);
    zero_f32<<<1, B, 0, stream>>>(g_sum, 256);
    edge_logits_k<1><<<cdiv((long)E, B), B, 0, stream>>>(as_, ad_, ei, ev, m_enc, E, flags);
    edge_exp_k<1><<<cdiv((long)E, B), B, 0, stream>>>(ev, m_enc, ei, s_sum, E, flags);
    edge_alpha_k<1><<<cdiv((long)E, B), B, 0, stream>>>(ev, s_sum, ei, d_out, off_a3, E, flags);
    edge_scatter_k<16, 1><<<cdiv((long)E * 16, B), B, 0, stream>>>(bufD, ev, s_sum, ei, bufE, E, flags);
    finalize3_k<<<cdiv((long)N * 16, B), B, 0, stream>>>(bufE, b3, batch, d_out, off_emb, g_sum, N, flags);

    // ---------------- Pool + classifier head ----------------
    head_k<<<1, B, 0, stream>>>(g_sum, batch, Wl, bl, d_out, off_gemb, N, flags);
}

// Round 4
// 1055.528 us; speedup vs baseline: 1.3976x; 1.3976x over previous
//
#include <hip/hip_runtime.h>
#include <hip/hip_bf16.h>

#define DEVFN __device__ __forceinline__

// ---- dual-dtype helpers: flags[0]=1 -> floats are f32 (else bf16);
//                          flags[1]=1 -> ints are int64 (else int32)
DEVFN float ldf(const void* p, size_t i, bool f32) {
    return f32 ? ((const float*)p)[i]
               : __bfloat162float(((const __hip_bfloat16*)p)[i]);
}
DEVFN int ldidx(const void* p, size_t i, bool i64) {
    return i64 ? (int)((const long long*)p)[i] : ((const int*)p)[i];
}
DEVFN void stf(void* p, size_t i, float v, bool f32) {
    if (f32) ((float*)p)[i] = v;
    else     ((__hip_bfloat16*)p)[i] = __float2bfloat16(v);
}

// monotonic float<->uint encoding for atomicMax-based segment max
DEVFN unsigned enc_f(float f) {
    unsigned b = __float_as_uint(f);
    return (b & 0x80000000u) ? ~b : (b | 0x80000000u);
}
DEVFN float dec_f(unsigned u) {
    return (u & 0x80000000u) ? __uint_as_float(u ^ 0x80000000u) : __uint_as_float(~u);
}

__global__ void detect_k(const void* x, const void* ei, int* flags) {
    if (threadIdx.x == 0 && blockIdx.x == 0) {
        const __hip_bfloat16* xb = (const __hip_bfloat16*)x;
        int bad = 0;
        for (int i = 0; i < 512; ++i) {
            float v = __bfloat162float(xb[i]);
            if (!(v == v) || fabsf(v) > 1.0e6f) bad++;
        }
        flags[0] = (bad > 16) ? 1 : 0;
        const unsigned* w = (const unsigned*)ei;
        int zeros = 0;
        for (int i = 0; i < 64; ++i) if (w[2 * i + 1] == 0u) zeros++;
        flags[1] = (zeros >= 60) ? 1 : 0;
    }
}

__global__ void zero_i32(int* __restrict__ p, int n) {
    int i = blockIdx.x * blockDim.x + threadIdx.x;
    int st = gridDim.x * blockDim.x;
    for (; i < n; i += st) p[i] = 0;
}
__global__ void zero_f32(float* __restrict__ p, long n) {
    long i = (long)blockIdx.x * blockDim.x + threadIdx.x;
    long st = (long)gridDim.x * blockDim.x;
    for (; i < n; i += st) p[i] = 0.f;
}

// ---------------- CSR build (dst-sorted, eid only) ----------------
__global__ void hist_k(const void* __restrict__ ei, int E, int* __restrict__ cnt,
                       const int* __restrict__ flags) {
    const bool i64 = flags[1] != 0;
    int e = blockIdx.x * blockDim.x + threadIdx.x;
    if (e >= E) return;
    atomicAdd(&cnt[ldidx(ei, (size_t)E + e, i64)], 1);
}

__global__ void scan_block_k(const int* __restrict__ cnt, int* __restrict__ incl,
                             int* __restrict__ part, int N) {
    __shared__ int sm[256];
    int tid = threadIdx.x;
    int i = blockIdx.x * 256 + tid;
    int v = (i < N) ? cnt[i] : 0;
    sm[tid] = v;
    __syncthreads();
    for (int o = 1; o < 256; o <<= 1) {
        int t = (tid >= o) ? sm[tid - o] : 0;
        __syncthreads();
        sm[tid] += t;
        __syncthreads();
    }
    if (i < N) incl[i] = sm[tid];
    if (tid == 255) part[blockIdx.x] = sm[255];
}

__global__ void scan_part_k(int* __restrict__ part, int nb) {
    __shared__ int sm[256];
    __shared__ int off;
    int tid = threadIdx.x;
    if (tid == 0) off = 0;
    __syncthreads();
    for (int b = 0; b < nb; b += 256) {
        int i = b + tid;
        int v = (i < nb) ? part[i] : 0;
        sm[tid] = v;
        __syncthreads();
        for (int o = 1; o < 256; o <<= 1) {
            int t = (tid >= o) ? sm[tid - o] : 0;
            __syncthreads();
            sm[tid] += t;
            __syncthreads();
        }
        if (i < nb) part[i] = sm[tid] - v + off;  // exclusive + carry
        __syncthreads();
        if (tid == 255) off += sm[255];
        __syncthreads();
    }
}

// cur aliases incl (read-then-overwrite same index is safe)
__global__ void finalize_scan_k(int* __restrict__ incl_cur, const int* __restrict__ cnt,
                                const int* __restrict__ part, int* __restrict__ rs,
                                int N, int E) {
    int i = blockIdx.x * 256 + threadIdx.x;
    if (i >= N) return;
    int v = incl_cur[i] - cnt[i] + part[blockIdx.x];
    rs[i] = v;
    incl_cur[i] = v;
    if (i == N - 1) rs[N] = E;
}

__global__ void scatter_csr_k(const void* __restrict__ ei, int E, int* __restrict__ cur,
                              int* __restrict__ csr_eid, const int* __restrict__ flags) {
    const bool i64 = flags[1] != 0;
    int e = blockIdx.x * blockDim.x + threadIdx.x;
    if (e >= E) return;
    int d = ldidx(ei, (size_t)E + e, i64);
    int p = atomicAdd(&cur[d], 1);
    csr_eid[p] = e;
}

// ---------------- dense h = x@W + alpha dots (verbatim round 2) ----------------
template <bool XEXT, int FIN, int FOUT, int HEADS>
__global__ __launch_bounds__(128) void gemm_alpha_k(
    const void* __restrict__ xin, const void* __restrict__ Wv,
    const void* __restrict__ asv, const void* __restrict__ adv,
    float* __restrict__ h_out, float* __restrict__ as_out, float* __restrict__ ad_out,
    int N, const int* __restrict__ flags)
{
    const bool f32 = flags[0] != 0;
    constexpr int NPB = 128 / FOUT;
    __shared__ float xs[NPB][FIN];
    __shared__ float red[4];
    const int tid = threadIdx.x;
    const int node0 = blockIdx.x * NPB;

    for (int i = tid; i < NPB * FIN; i += 128) {
        int nl = i / FIN, k = i - nl * FIN;
        int n = node0 + nl;
        float v = 0.f;
        if (n < N) {
            size_t gi = (size_t)n * FIN + k;
            v = XEXT ? ldf(xin, gi, f32) : ((const float*)xin)[gi];
        }
        xs[nl][k] = v;
    }
    __syncthreads();

    const int nl = tid / FOUT;
    const int col = tid - nl * FOUT;
    const int n = node0 + nl;

    float acc = 0.f;
#pragma unroll 8
    for (int k = 0; k < FIN; ++k)
        acc = fmaf(xs[nl][k], ldf(Wv, (size_t)k * FOUT + col, f32), acc);

    if (n < N) h_out[(size_t)n * FOUT + col] = acc;

    float cs = acc * ldf(asv, col, f32);
    float cd = acc * ldf(adv, col, f32);

    if constexpr (FOUT == 128 && HEADS == 2) {
        for (int o = 32; o; o >>= 1) { cs += __shfl_down(cs, o); cd += __shfl_down(cd, o); }
        int w = tid >> 6;
        if ((tid & 63) == 0 && n < N) {
            as_out[(size_t)n * 2 + w] = cs;
            ad_out[(size_t)n * 2 + w] = cd;
        }
    } else if constexpr (FOUT == 128 && HEADS == 1) {
        for (int o = 32; o; o >>= 1) { cs += __shfl_down(cs, o); cd += __shfl_down(cd, o); }
        if ((tid & 63) == 0) { red[(tid >> 6)] = cs; red[2 + (tid >> 6)] = cd; }
        __syncthreads();
        if (tid == 0 && n < N) {
            as_out[n] = red[0] + red[1];
            ad_out[n] = red[2] + red[3];
        }
    } else {
        for (int o = 8; o; o >>= 1) { cs += __shfl_down(cs, o, 16); cd += __shfl_down(cd, o, 16); }
        if (col == 0 && n < N) { as_out[n] = cs; ad_out[n] = cd; }
    }
}

// ---------------- edge softmax kernels (verbatim round 2) ----------------
template <int HEADS>
__global__ void edge_logits_k(const float* __restrict__ as_, const float* __restrict__ ad_,
                              const void* __restrict__ ei, float* __restrict__ logits,
                              unsigned* __restrict__ m_enc, int E, const int* __restrict__ flags)
{
    const bool i64 = flags[1] != 0;
    int idx = blockIdx.x * blockDim.x + threadIdx.x;
    if (idx >= E * HEADS) return;
    int e = idx / HEADS, h = idx - (idx / HEADS) * HEADS;
    int s_ = ldidx(ei, e, i64);
    int d_ = ldidx(ei, (size_t)E + e, i64);
    float lg = as_[(size_t)s_ * HEADS + h] + ad_[(size_t)d_ * HEADS + h];
    lg = lg > 0.f ? lg : 0.2f * lg;  // leaky_relu 0.2
    logits[idx] = lg;
    atomicMax(&m_enc[(size_t)d_ * HEADS + h], enc_f(lg));
}

template <int HEADS>
__global__ void edge_exp_k(float* __restrict__ ev, const unsigned* __restrict__ m_enc,
                           const void* __restrict__ ei, float* __restrict__ s_sum,
                           int E, const int* __restrict__ flags)
{
    const bool i64 = flags[1] != 0;
    int idx = blockIdx.x * blockDim.x + threadIdx.x;
    if (idx >= E * HEADS) return;
    int e = idx / HEADS, h = idx - (idx / HEADS) * HEADS;
    int d_ = ldidx(ei, (size_t)E + e, i64);
    float m = dec_f(m_enc[(size_t)d_ * HEADS + h]);
    float x = expf(ev[idx] - m);
    ev[idx] = x;
    atomicAdd(&s_sum[(size_t)d_ * HEADS + h], x);
}

template <int HEADS>
__global__ void edge_alpha_k(const float* __restrict__ ev, const float* __restrict__ s_sum,
                             const void* __restrict__ ei, void* __restrict__ dout,
                             size_t aoff, int E, const int* __restrict__ flags)
{
    const bool f32 = flags[0] != 0;
    const bool i64 = flags[1] != 0;
    int idx = blockIdx.x * blockDim.x + threadIdx.x;
    if (idx >= E * HEADS) return;
    int e = idx / HEADS, h = idx - (idx / HEADS) * HEADS;
    int d_ = ldidx(ei, (size_t)E + e, i64);
    float a = ev[idx] / (s_sum[(size_t)d_ * HEADS + h] + 1e-16f);
    stf(dout, aoff + idx, a, f32);
}

// ---------------- NEW: CSR pull message-sum, FOUT=128, one block per node ----------------
template <int HEADS, bool RELU>
__global__ __launch_bounds__(128) void pull128_k(
    const float* __restrict__ h_t, const float* __restrict__ ev,
    const float* __restrict__ s_sum, const void* __restrict__ ei,
    const int* __restrict__ rs, const int* __restrict__ csr_eid,
    const void* __restrict__ bias, float* __restrict__ out,
    int N, int E, const int* __restrict__ flags)
{
    const bool f32 = flags[0] != 0;
    const bool i64 = flags[1] != 0;
    const int d = blockIdx.x;
    if (d >= N) return;
    const int col = threadIdx.x;
    const int h = (HEADS == 2) ? (col >> 6) : 0;
    const float inv = 1.f / (s_sum[(size_t)d * HEADS + h] + 1e-16f);
    const int beg = rs[d], end = rs[d + 1];
    float acc = 0.f;
    for (int p = beg; p < end; ++p) {
        int ej = csr_eid[p];
        int sj = ldidx(ei, ej, i64);
        float a = ev[(size_t)ej * HEADS + h] * inv;
        acc = fmaf(h_t[(size_t)sj * 128 + col], a, acc);
    }
    float v = acc + ldf(bias, col, f32);
    if (RELU) v = fmaxf(v, 0.f);
    out[(size_t)d * 128 + col] = v;
}

// ---------------- layer-3 atomic scatter (verbatim round 2) ----------------
template <int FOUT, int HEADS>
__global__ void edge_scatter_k(const float* __restrict__ h_t, const float* __restrict__ ev,
                               const float* __restrict__ s_sum, const void* __restrict__ ei,
                               float* __restrict__ acc, int E, const int* __restrict__ flags)
{
    const bool i64 = flags[1] != 0;
    constexpr int C = FOUT / HEADS;
    long idx = (long)blockIdx.x * blockDim.x + threadIdx.x;
    if (idx >= (long)E * FOUT) return;
    int e = (int)(idx / FOUT);
    int col = (int)(idx & (FOUT - 1));
    int h = col / C;
    int s_ = ldidx(ei, e, i64);
    int d_ = ldidx(ei, (size_t)E + e, i64);
    float alpha = ev[(size_t)e * HEADS + h] / (s_sum[(size_t)d_ * HEADS + h] + 1e-16f);
    atomicAdd(&acc[(size_t)d_ * FOUT + col], h_t[(size_t)s_ * FOUT + col] * alpha);
}

// layer3 finalize: emb = acc + b3, write emb to d_out, pool per-graph sums
__global__ __launch_bounds__(256) void finalize3_k(
    const float* __restrict__ acc, const void* __restrict__ bias,
    const void* __restrict__ batch, void* __restrict__ dout, size_t emb_off,
    float* __restrict__ g_sum, int N, const int* __restrict__ flags)
{
    const bool f32 = flags[0] != 0;
    const bool i64 = flags[1] != 0;
    __shared__ float gp[256];
    int tid = threadIdx.x;
    gp[tid] = 0.f;
    __syncthreads();
    long idx = (long)blockIdx.x * 256 + tid;
    if (idx < (long)N * 16) {
        int n = (int)(idx >> 4), col = (int)(idx & 15);
        float v = acc[idx] + ldf(bias, col, f32);
        stf(dout, emb_off + idx, v, f32);
        int g = ldidx(batch, n, i64);
        atomicAdd(&gp[g * 16 + col], v);
    }
    __syncthreads();
    float pv = gp[tid];
    if (pv != 0.f) atomicAdd(&g_sum[tid], pv);
}

__global__ __launch_bounds__(256) void head_k(
    const float* __restrict__ g_sum, const void* __restrict__ batch,
    const void* __restrict__ Wl, const void* __restrict__ bl,
    void* __restrict__ dout, size_t gemb_off, int N, const int* __restrict__ flags)
{
    const bool f32 = flags[0] != 0;
    const bool i64 = flags[1] != 0;
    __shared__ float ge[256];
    __shared__ int cnts[16];
    int tid = threadIdx.x;
    if (tid < 16) {
        int lo = 0, hi = N;
        while (lo < hi) { int mid = (lo + hi) >> 1; if (ldidx(batch, mid, i64) < tid) lo = mid + 1; else hi = mid; }
        int l2 = 0, h2 = N;
        while (l2 < h2) { int mid = (l2 + h2) >> 1; if (ldidx(batch, mid, i64) <= tid) l2 = mid + 1; else h2 = mid; }
        cnts[tid] = l2 - lo;
    }
    __syncthreads();
    {
        int g = tid >> 4;
        float v = g_sum[tid] / fmaxf((float)cnts[g], 1.f);
        ge[tid] = v;
        stf(dout, gemb_off + tid, v, f32);
    }
    __syncthreads();
    if (tid < 32) {
        int g = tid >> 1, j = tid & 1;
        float s = ldf(bl, j, f32);
        for (int c = 0; c < 16; ++c) s += ge[g * 16 + c] * ldf(Wl, (size_t)c * 2 + j, f32);
        stf(dout, (size_t)g * 2 + j, s, f32);
    }
}

static inline int cdiv(long a, int b) { return (int)((a + b - 1) / b); }

extern "C" void kernel_launch(void* const* d_in, const int* in_sizes, int n_in,
                              void* d_out, int out_size, void* d_ws, size_t ws_size,
                              hipStream_t stream)
{
    const void* x   = d_in[0];
    const void* ei  = d_in[1];
    const void* batch = d_in[2];
    const void* W1  = d_in[3];
    const void* as1 = d_in[4];
    const void* ad1 = d_in[5];
    const void* b1  = d_in[6];
    const void* W2  = d_in[7];
    const void* as2 = d_in[8];
    const void* ad2 = d_in[9];
    const void* b2  = d_in[10];
    const void* W3  = d_in[11];
    const void* as3 = d_in[12];
    const void* ad3 = d_in[13];
    const void* b3  = d_in[14];
    const void* Wl  = d_in[15];
    const void* bl  = d_in[16];

    const int N = in_sizes[0] / 128;
    const int E = in_sizes[1] / 2;

    int* flags = (int*)d_ws;
    float* ws = (float*)d_ws + 16;
    size_t o = 0;
    float* bufA = ws + o; o += (size_t)N * 128;   // h_t; layer3 bufs alias it
    float* bufB = ws + o; o += (size_t)N * 128;   // layer output / next input
    float* bufD = bufA;                           // layer3 h_t
    float* bufE = bufA + (size_t)N * 16;          // layer3 acc
    float* as_  = ws + o; o += (size_t)N * 2;
    float* ad_  = ws + o; o += (size_t)N * 2;
    unsigned* m_enc = (unsigned*)(ws + o); o += (size_t)N * 2;
    float* s_sum = ws + o; o += (size_t)N * 2;
    float* ev   = ws + o; o += (size_t)E * 2;
    float* g_sum = ws + o; o += 256;
    int* ip = (int*)(ws + o);
    int* cnt  = ip;            ip += N;
    int* incl = ip;            ip += N;   // reused as `cur` after finalize_scan
    int* part = ip;            ip += 256;
    int* rs   = ip;            ip += N + 1;
    int* csr_eid = ip;         ip += E;

    const size_t off_gemb = 32;
    const size_t off_emb  = 32 + 256;
    const size_t off_a1   = off_emb + (size_t)N * 16;
    const size_t off_a2   = off_a1 + (size_t)E * 2;
    const size_t off_a3   = off_a2 + (size_t)E;

    const int B = 256;
    const int nbN = cdiv(N, 256);

    detect_k<<<1, 64, 0, stream>>>(x, ei, flags);

    // ---- CSR build (dst-sorted edge ids), reused by all layers ----
    zero_i32<<<nbN, B, 0, stream>>>(cnt, N);
    hist_k<<<cdiv(E, B), B, 0, stream>>>(ei, E, cnt, flags);
    scan_block_k<<<nbN, B, 0, stream>>>(cnt, incl, part, N);
    scan_part_k<<<1, B, 0, stream>>>(part, nbN);
    finalize_scan_k<<<nbN, B, 0, stream>>>(incl, cnt, part, rs, N, E);
    scatter_csr_k<<<cdiv(E, B), B, 0, stream>>>(ei, E, incl, csr_eid, flags);

    // ---------------- Layer 1: 128 -> (2 heads x 64), concat, relu ----------------
    gemm_alpha_k<true, 128, 128, 2><<<N, 128, 0, stream>>>(x, W1, as1, ad1, bufA, as_, ad_, N, flags);
    zero_f32<<<cdiv((long)N * 2, B), B, 0, stream>>>((float*)m_enc, (long)N * 2);
    zero_f32<<<cdiv((long)N * 2, B), B, 0, stream>>>(s_sum, (long)N * 2);
    edge_logits_k<2><<<cdiv((long)E * 2, B), B, 0, stream>>>(as_, ad_, ei, ev, m_enc, E, flags);
    edge_exp_k<2><<<cdiv((long)E * 2, B), B, 0, stream>>>(ev, m_enc, ei, s_sum, E, flags);
    edge_alpha_k<2><<<cdiv((long)E * 2, B), B, 0, stream>>>(ev, s_sum, ei, d_out, off_a1, E, flags);
    pull128_k<2, true><<<N, 128, 0, stream>>>(bufA, ev, s_sum, ei, rs, csr_eid, b1, bufB, N, E, flags);

    // ---------------- Layer 2: 128 -> 128, 1 head, mean(=identity), relu ----------------
    gemm_alpha_k<false, 128, 128, 1><<<N, 128, 0, stream>>>(bufB, W2, as2, ad2, bufA, as_, ad_, N, flags);
    zero_f32<<<cdiv((long)N, B), B, 0, stream>>>((float*)m_enc, (long)N);
    zero_f32<<<cdiv((long)N, B), B, 0, stream>>>(s_sum, (long)N);
    edge_logits_k<1><<<cdiv((long)E, B), B, 0, stream>>>(as_, ad_, ei, ev, m_enc, E, flags);
    edge_exp_k<1><<<cdiv((long)E, B), B, 0, stream>>>(ev, m_enc, ei, s_sum, E, flags);
    edge_alpha_k<1><<<cdiv((long)E, B), B, 0, stream>>>(ev, s_sum, ei, d_out, off_a2, E, flags);
    pull128_k<1, true><<<N, 128, 0, stream>>>(bufA, ev, s_sum, ei, rs, csr_eid, b2, bufB, N, E, flags);

    // ---------------- Layer 3: 128 -> 16, 1 head, mean(=identity), no relu ----------------
    gemm_alpha_k<false, 128, 16, 1><<<cdiv(N, 8), 128, 0, stream>>>(bufB, W3, as3, ad3, bufD, as_, ad_, N, flags);
    zero_f32<<<cdiv((long)N, B), B, 0, stream>>>((float*)m_enc, (long)N);
    zero_f32<<<cdiv((long)N, B), B, 0, stream>>>(s_sum, (long)N);
    zero_f32<<<cdiv((long)N * 16, B), B, 0, stream>>>(bufE, (long)N * 16);
    zero_f32<<<1, B, 0, stream>>>(g_sum, 256);
    edge_logits_k<1><<<cdiv((long)E, B), B, 0, stream>>>(as_, ad_, ei, ev, m_enc, E, flags);
    edge_exp_k<1><<<cdiv((long)E, B), B, 0, stream>>>(ev, m_enc, ei, s_sum, E, flags);
    edge_alpha_k<1><<<cdiv((long)E, B), B, 0, stream>>>(ev, s_sum, ei, d_out, off_a3, E, flags);
    edge_scatter_k<16, 1><<<cdiv((long)E * 16, B), B, 0, stream>>>(bufD, ev, s_sum, ei, bufE, E, flags);
    finalize3_k<<<cdiv((long)N * 16, B), B, 0, stream>>>(bufE, b3, batch, d_out, off_emb, g_sum, N, flags);

    // ---------------- Pool + classifier head ----------------
    head_k<<<1, B, 0, stream>>>(g_sum, batch, Wl, bl, d_out, off_gemb, N, flags);
}

// Round 5
// 683.983 us; speedup vs baseline: 2.1568x; 1.5432x over previous
//
#include <hip/hip_runtime.h>
#include <hip/hip_bf16.h>

#define DEVFN __device__ __forceinline__

// ---- dual-dtype helpers: flags[0]=1 -> floats are f32 (else bf16);
//                          flags[1]=1 -> ints are int64 (else int32)
DEVFN float ldf(const void* p, size_t i, bool f32) {
    return f32 ? ((const float*)p)[i]
               : __bfloat162float(((const __hip_bfloat16*)p)[i]);
}
DEVFN int ldidx(const void* p, size_t i, bool i64) {
    return i64 ? (int)((const long long*)p)[i] : ((const int*)p)[i];
}
DEVFN void stf(void* p, size_t i, float v, bool f32) {
    if (f32) ((float*)p)[i] = v;
    else     ((__hip_bfloat16*)p)[i] = __float2bfloat16(v);
}
DEVFN float lky(float v) { return v > 0.f ? v : 0.2f * v; }

__global__ void detect_k(const void* x, const void* ei, int* flags) {
    if (threadIdx.x == 0 && blockIdx.x == 0) {
        const __hip_bfloat16* xb = (const __hip_bfloat16*)x;
        int bad = 0;
        for (int i = 0; i < 512; ++i) {
            float v = __bfloat162float(xb[i]);
            if (!(v == v) || fabsf(v) > 1.0e6f) bad++;
        }
        flags[0] = (bad > 16) ? 1 : 0;
        const unsigned* w = (const unsigned*)ei;
        int zeros = 0;
        for (int i = 0; i < 64; ++i) if (w[2 * i + 1] == 0u) zeros++;
        flags[1] = (zeros >= 60) ? 1 : 0;
    }
}

__global__ void zero_i32(int* __restrict__ p, int n) {
    int i = blockIdx.x * blockDim.x + threadIdx.x;
    int st = gridDim.x * blockDim.x;
    for (; i < n; i += st) p[i] = 0;
}
__global__ void zero_f32(float* __restrict__ p, long n) {
    long i = (long)blockIdx.x * blockDim.x + threadIdx.x;
    long st = (long)gridDim.x * blockDim.x;
    for (; i < n; i += st) p[i] = 0.f;
}

// ---------------- CSR build (dst-sorted) ----------------
__global__ void hist_k(const void* __restrict__ ei, int E, int* __restrict__ cnt,
                       const int* __restrict__ flags) {
    const bool i64 = flags[1] != 0;
    int e = blockIdx.x * blockDim.x + threadIdx.x;
    if (e >= E) return;
    atomicAdd(&cnt[ldidx(ei, (size_t)E + e, i64)], 1);
}

__global__ void scan_block_k(const int* __restrict__ cnt, int* __restrict__ incl,
                             int* __restrict__ part, int N) {
    __shared__ int sm[256];
    int tid = threadIdx.x;
    int i = blockIdx.x * 256 + tid;
    int v = (i < N) ? cnt[i] : 0;
    sm[tid] = v;
    __syncthreads();
    for (int o = 1; o < 256; o <<= 1) {
        int t = (tid >= o) ? sm[tid - o] : 0;
        __syncthreads();
        sm[tid] += t;
        __syncthreads();
    }
    if (i < N) incl[i] = sm[tid];
    if (tid == 255) part[blockIdx.x] = sm[255];
}

__global__ void scan_part_k(int* __restrict__ part, int nb) {
    __shared__ int sm[256];
    __shared__ int off;
    int tid = threadIdx.x;
    if (tid == 0) off = 0;
    __syncthreads();
    for (int b = 0; b < nb; b += 256) {
        int i = b + tid;
        int v = (i < nb) ? part[i] : 0;
        sm[tid] = v;
        __syncthreads();
        for (int o = 1; o < 256; o <<= 1) {
            int t = (tid >= o) ? sm[tid - o] : 0;
            __syncthreads();
            sm[tid] += t;
            __syncthreads();
        }
        if (i < nb) part[i] = sm[tid] - v + off;  // exclusive + carry
        __syncthreads();
        if (tid == 255) off += sm[255];
        __syncthreads();
    }
}

// cur aliases incl (read-then-overwrite same index is safe)
__global__ void finalize_scan_k(int* __restrict__ incl_cur, const int* __restrict__ cnt,
                                const int* __restrict__ part, int* __restrict__ rs,
                                int N, int E) {
    int i = blockIdx.x * 256 + threadIdx.x;
    if (i >= N) return;
    int v = incl_cur[i] - cnt[i] + part[blockIdx.x];
    rs[i] = v;
    incl_cur[i] = v;
    if (i == N - 1) rs[N] = E;
}

__global__ void scatter_csr_k(const void* __restrict__ ei, int E, int* __restrict__ cur,
                              int* __restrict__ csr_src, int* __restrict__ csr_eid,
                              const int* __restrict__ flags) {
    const bool i64 = flags[1] != 0;
    int e = blockIdx.x * blockDim.x + threadIdx.x;
    if (e >= E) return;
    int s = ldidx(ei, e, i64);
    int d = ldidx(ei, (size_t)E + e, i64);
    int p = atomicAdd(&cur[d], 1);
    csr_src[p] = s;
    csr_eid[p] = e;
}

// ---------------- dense h = x@W + alpha dots (verbatim round 2/4) ----------------
template <bool XEXT, int FIN, int FOUT, int HEADS>
__global__ __launch_bounds__(128) void gemm_alpha_k(
    const void* __restrict__ xin, const void* __restrict__ Wv,
    const void* __restrict__ asv, const void* __restrict__ adv,
    float* __restrict__ h_out, float* __restrict__ as_out, float* __restrict__ ad_out,
    int N, const int* __restrict__ flags)
{
    const bool f32 = flags[0] != 0;
    constexpr int NPB = 128 / FOUT;
    __shared__ float xs[NPB][FIN];
    __shared__ float red[4];
    const int tid = threadIdx.x;
    const int node0 = blockIdx.x * NPB;

    for (int i = tid; i < NPB * FIN; i += 128) {
        int nl = i / FIN, k = i - nl * FIN;
        int n = node0 + nl;
        float v = 0.f;
        if (n < N) {
            size_t gi = (size_t)n * FIN + k;
            v = XEXT ? ldf(xin, gi, f32) : ((const float*)xin)[gi];
        }
        xs[nl][k] = v;
    }
    __syncthreads();

    const int nl = tid / FOUT;
    const int col = tid - nl * FOUT;
    const int n = node0 + nl;

    float acc = 0.f;
#pragma unroll 8
    for (int k = 0; k < FIN; ++k)
        acc = fmaf(xs[nl][k], ldf(Wv, (size_t)k * FOUT + col, f32), acc);

    if (n < N) h_out[(size_t)n * FOUT + col] = acc;

    float cs = acc * ldf(asv, col, f32);
    float cd = acc * ldf(adv, col, f32);

    if constexpr (FOUT == 128 && HEADS == 2) {
        for (int o = 32; o; o >>= 1) { cs += __shfl_down(cs, o); cd += __shfl_down(cd, o); }
        int w = tid >> 6;
        if ((tid & 63) == 0 && n < N) {
            as_out[(size_t)n * 2 + w] = cs;
            ad_out[(size_t)n * 2 + w] = cd;
        }
    } else if constexpr (FOUT == 128 && HEADS == 1) {
        for (int o = 32; o; o >>= 1) { cs += __shfl_down(cs, o); cd += __shfl_down(cd, o); }
        if ((tid & 63) == 0) { red[(tid >> 6)] = cs; red[2 + (tid >> 6)] = cd; }
        __syncthreads();
        if (tid == 0 && n < N) {
            as_out[n] = red[0] + red[1];
            ad_out[n] = red[2] + red[3];
        }
    } else {
        for (int o = 8; o; o >>= 1) { cs += __shfl_down(cs, o, 16); cd += __shfl_down(cd, o, 16); }
        if (col == 0 && n < N) { as_out[n] = cs; ad_out[n] = cd; }
    }
}

// ---------------- NEW: fused per-node segment softmax over CSR ----------------
// one wave per node; writes final alpha CSR-ordered (alpha_csr) and eid-ordered (d_out)
template <int HEADS>
__global__ __launch_bounds__(256) void softmax_csr_k(
    const float* __restrict__ as_, const float* __restrict__ ad_,
    const int* __restrict__ rs, const int* __restrict__ csr_src, const int* __restrict__ csr_eid,
    float* __restrict__ alpha_csr, void* __restrict__ dout, size_t aoff,
    int N, const int* __restrict__ flags)
{
    const bool f32 = flags[0] != 0;
    const int wid = (blockIdx.x * 256 + threadIdx.x) >> 6;
    const int lane = threadIdx.x & 63;
    if (wid >= N) return;
    const int beg = rs[wid], end = rs[wid + 1];

    const float ad0 = ad_[(size_t)wid * HEADS];
    const float ad1 = (HEADS == 2) ? ad_[(size_t)wid * HEADS + 1] : 0.f;

    // pass 1: max
    float m0 = -1e30f, m1 = -1e30f;
    for (int p = beg + lane; p < end; p += 64) {
        int s = csr_src[p];
        m0 = fmaxf(m0, lky(as_[(size_t)s * HEADS] + ad0));
        if (HEADS == 2) m1 = fmaxf(m1, lky(as_[(size_t)s * HEADS + 1] + ad1));
    }
    for (int o = 1; o < 64; o <<= 1) {
        m0 = fmaxf(m0, __shfl_xor(m0, o));
        if (HEADS == 2) m1 = fmaxf(m1, __shfl_xor(m1, o));
    }
    // pass 2: sum of exp
    float s0 = 0.f, s1 = 0.f;
    for (int p = beg + lane; p < end; p += 64) {
        int s = csr_src[p];
        s0 += expf(lky(as_[(size_t)s * HEADS] + ad0) - m0);
        if (HEADS == 2) s1 += expf(lky(as_[(size_t)s * HEADS + 1] + ad1) - m1);
    }
    for (int o = 1; o < 64; o <<= 1) {
        s0 += __shfl_xor(s0, o);
        if (HEADS == 2) s1 += __shfl_xor(s1, o);
    }
    const float inv0 = 1.f / (s0 + 1e-16f);
    const float inv1 = 1.f / (s1 + 1e-16f);

    // pass 3: write alpha (CSR-ordered stream + eid-ordered d_out)
    for (int p = beg + lane; p < end; p += 64) {
        int s = csr_src[p];
        int eid = csr_eid[p];
        float a0 = expf(lky(as_[(size_t)s * HEADS] + ad0) - m0) * inv0;
        alpha_csr[(size_t)p * HEADS] = a0;
        stf(dout, aoff + (size_t)eid * HEADS, a0, f32);
        if (HEADS == 2) {
            float a1 = expf(lky(as_[(size_t)s * HEADS + 1] + ad1) - m1) * inv1;
            alpha_csr[(size_t)p * 2 + 1] = a1;
            stf(dout, aoff + (size_t)eid * 2 + 1, a1, f32);
        }
    }
}

// ---------------- CSR pull message-sum, FOUT=128 (proven structure) ----------------
template <int HEADS, bool RELU>
__global__ __launch_bounds__(128) void pull128_k(
    const float* __restrict__ h_t, const float* __restrict__ alpha_csr,
    const int* __restrict__ rs, const int* __restrict__ csr_src,
    const void* __restrict__ bias, float* __restrict__ out,
    int N, const int* __restrict__ flags)
{
    const bool f32 = flags[0] != 0;
    const int d = blockIdx.x;
    if (d >= N) return;
    const int col = threadIdx.x;
    const int h = (HEADS == 2) ? (col >> 6) : 0;
    const int beg = rs[d], end = rs[d + 1];
    float acc = 0.f;
    for (int p = beg; p < end; ++p) {
        int sj = csr_src[p];
        float a = alpha_csr[(size_t)p * HEADS + h];
        acc = fmaf(h_t[(size_t)sj * 128 + col], a, acc);
    }
    float v = acc + ldf(bias, col, f32);
    if (RELU) v = fmaxf(v, 0.f);
    out[(size_t)d * 128 + col] = v;
}

// ---------------- CSR pull, FOUT=16: 8 nodes/block, 16 lanes each ----------------
__global__ __launch_bounds__(128) void pull16_k(
    const float* __restrict__ h_t, const float* __restrict__ alpha_csr,
    const int* __restrict__ rs, const int* __restrict__ csr_src,
    float* __restrict__ out, int N)
{
    const int g = threadIdx.x >> 4;
    const int c = threadIdx.x & 15;
    const int d = blockIdx.x * 8 + g;
    if (d >= N) return;
    const int beg = rs[d], end = rs[d + 1];
    float acc = 0.f;
    for (int p = beg; p < end; ++p)
        acc = fmaf(h_t[(size_t)csr_src[p] * 16 + c], alpha_csr[p], acc);
    out[(size_t)d * 16 + c] = acc;
}

// layer3 finalize: emb = acc + b3, write emb to d_out, pool per-graph sums
__global__ __launch_bounds__(256) void finalize3_k(
    const float* __restrict__ acc, const void* __restrict__ bias,
    const void* __restrict__ batch, void* __restrict__ dout, size_t emb_off,
    float* __restrict__ g_sum, int N, const int* __restrict__ flags)
{
    const bool f32 = flags[0] != 0;
    const bool i64 = flags[1] != 0;
    __shared__ float gp[256];
    int tid = threadIdx.x;
    gp[tid] = 0.f;
    __syncthreads();
    long idx = (long)blockIdx.x * 256 + tid;
    if (idx < (long)N * 16) {
        int n = (int)(idx >> 4), col = (int)(idx & 15);
        float v = acc[idx] + ldf(bias, col, f32);
        stf(dout, emb_off + idx, v, f32);
        int g = ldidx(batch, n, i64);
        atomicAdd(&gp[g * 16 + col], v);
    }
    __syncthreads();
    float pv = gp[tid];
    if (pv != 0.f) atomicAdd(&g_sum[tid], pv);
}

__global__ __launch_bounds__(256) void head_k(
    const float* __restrict__ g_sum, const void* __restrict__ batch,
    const void* __restrict__ Wl, const void* __restrict__ bl,
    void* __restrict__ dout, size_t gemb_off, int N, const int* __restrict__ flags)
{
    const bool f32 = flags[0] != 0;
    const bool i64 = flags[1] != 0;
    __shared__ float ge[256];
    __shared__ int cnts[16];
    int tid = threadIdx.x;
    if (tid < 16) {
        int lo = 0, hi = N;
        while (lo < hi) { int mid = (lo + hi) >> 1; if (ldidx(batch, mid, i64) < tid) lo = mid + 1; else hi = mid; }
        int l2 = 0, h2 = N;
        while (l2 < h2) { int mid = (l2 + h2) >> 1; if (ldidx(batch, mid, i64) <= tid) l2 = mid + 1; else h2 = mid; }
        cnts[tid] = l2 - lo;
    }
    __syncthreads();
    {
        int g = tid >> 4;
        float v = g_sum[tid] / fmaxf((float)cnts[g], 1.f);
        ge[tid] = v;
        stf(dout, gemb_off + tid, v, f32);
    }
    __syncthreads();
    if (tid < 32) {
        int g = tid >> 1, j = tid & 1;
        float s = ldf(bl, j, f32);
        for (int c = 0; c < 16; ++c) s += ge[g * 16 + c] * ldf(Wl, (size_t)c * 2 + j, f32);
        stf(dout, (size_t)g * 2 + j, s, f32);
    }
}

static inline int cdiv(long a, int b) { return (int)((a + b - 1) / b); }

extern "C" void kernel_launch(void* const* d_in, const int* in_sizes, int n_in,
                              void* d_out, int out_size, void* d_ws, size_t ws_size,
                              hipStream_t stream)
{
    const void* x   = d_in[0];
    const void* ei  = d_in[1];
    const void* batch = d_in[2];
    const void* W1  = d_in[3];
    const void* as1 = d_in[4];
    const void* ad1 = d_in[5];
    const void* b1  = d_in[6];
    const void* W2  = d_in[7];
    const void* as2 = d_in[8];
    const void* ad2 = d_in[9];
    const void* b2  = d_in[10];
    const void* W3  = d_in[11];
    const void* as3 = d_in[12];
    const void* ad3 = d_in[13];
    const void* b3  = d_in[14];
    const void* Wl  = d_in[15];
    const void* bl  = d_in[16];

    const int N = in_sizes[0] / 128;
    const int E = in_sizes[1] / 2;

    int* flags = (int*)d_ws;
    float* ws = (float*)d_ws + 16;
    size_t o = 0;
    float* bufA = ws + o; o += (size_t)N * 128;   // h_t; layer3 bufs alias it
    float* bufB = ws + o; o += (size_t)N * 128;   // layer output / next input
    float* bufD = bufA;                           // layer3 h_t
    float* bufE = bufA + (size_t)N * 16;          // layer3 agg out
    float* as_  = ws + o; o += (size_t)N * 2;
    float* ad_  = ws + o; o += (size_t)N * 2;
    float* alpha_csr = ws + o; o += (size_t)E * 2;
    float* g_sum = ws + o; o += 256;
    int* ip = (int*)(ws + o);
    int* cnt  = ip;            ip += N;
    int* incl = ip;            ip += N;   // reused as `cur` after finalize_scan
    int* part = ip;            ip += 256;
    int* rs   = ip;            ip += N + 1;
    int* csr_src = ip;         ip += E;
    int* csr_eid = ip;         ip += E;

    const size_t off_gemb = 32;
    const size_t off_emb  = 32 + 256;
    const size_t off_a1   = off_emb + (size_t)N * 16;
    const size_t off_a2   = off_a1 + (size_t)E * 2;
    const size_t off_a3   = off_a2 + (size_t)E;

    const int B = 256;
    const int nbN = cdiv(N, 256);

    detect_k<<<1, 64, 0, stream>>>(x, ei, flags);

    // ---- CSR build (dst-sorted src + edge ids), reused by all layers ----
    zero_i32<<<nbN, B, 0, stream>>>(cnt, N);
    hist_k<<<cdiv(E, B), B, 0, stream>>>(ei, E, cnt, flags);
    scan_block_k<<<nbN, B, 0, stream>>>(cnt, incl, part, N);
    scan_part_k<<<1, B, 0, stream>>>(part, nbN);
    finalize_scan_k<<<nbN, B, 0, stream>>>(incl, cnt, part, rs, N, E);
    scatter_csr_k<<<cdiv(E, B), B, 0, stream>>>(ei, E, incl, csr_src, csr_eid, flags);

    // ---------------- Layer 1: 128 -> (2 heads x 64), concat, relu ----------------
    gemm_alpha_k<true, 128, 128, 2><<<N, 128, 0, stream>>>(x, W1, as1, ad1, bufA, as_, ad_, N, flags);
    softmax_csr_k<2><<<cdiv(N, 4), 256, 0, stream>>>(as_, ad_, rs, csr_src, csr_eid,
                                                     alpha_csr, d_out, off_a1, N, flags);
    pull128_k<2, true><<<N, 128, 0, stream>>>(bufA, alpha_csr, rs, csr_src, b1, bufB, N, flags);

    // ---------------- Layer 2: 128 -> 128, 1 head, mean(=identity), relu ----------------
    gemm_alpha_k<false, 128, 128, 1><<<N, 128, 0, stream>>>(bufB, W2, as2, ad2, bufA, as_, ad_, N, flags);
    softmax_csr_k<1><<<cdiv(N, 4), 256, 0, stream>>>(as_, ad_, rs, csr_src, csr_eid,
                                                     alpha_csr, d_out, off_a2, N, flags);
    pull128_k<1, true><<<N, 128, 0, stream>>>(bufA, alpha_csr, rs, csr_src, b2, bufB, N, flags);

    // ---------------- Layer 3: 128 -> 16, 1 head, mean(=identity), no relu ----------------
    gemm_alpha_k<false, 128, 16, 1><<<cdiv(N, 8), 128, 0, stream>>>(bufB, W3, as3, ad3, bufD, as_, ad_, N, flags);
    softmax_csr_k<1><<<cdiv(N, 4), 256, 0, stream>>>(as_, ad_, rs, csr_src, csr_eid,
                                                     alpha_csr, d_out, off_a3, N, flags);
    pull16_k<<<cdiv(N, 8), 128, 0, stream>>>(bufD, alpha_csr, rs, csr_src, bufE, N);
    zero_f32<<<1, B, 0, stream>>>(g_sum, 256);
    finalize3_k<<<cdiv((long)N * 16, B), B, 0, stream>>>(bufE, b3, batch, d_out, off_emb, g_sum, N, flags);

    // ---------------- Pool + classifier head ----------------
    head_k<<<1, B, 0, stream>>>(g_sum, batch, Wl, bl, d_out, off_gemb, N, flags);
}

// Round 6
// 484.445 us; speedup vs baseline: 3.0451x; 1.4119x over previous
//
#include <hip/hip_runtime.h>
#include <hip/hip_bf16.h>

#define DEVFN __device__ __forceinline__

using short8 = __attribute__((ext_vector_type(8))) short;
using f32x4  = __attribute__((ext_vector_type(4))) float;

// ---- dual-dtype helpers: flags[0]=1 -> floats are f32 (else bf16);
//                          flags[1]=1 -> ints are int64 (else int32)
DEVFN float ldf(const void* p, size_t i, bool f32) {
    return f32 ? ((const float*)p)[i]
               : __bfloat162float(((const __hip_bfloat16*)p)[i]);
}
DEVFN int ldidx(const void* p, size_t i, bool i64) {
    return i64 ? (int)((const long long*)p)[i] : ((const int*)p)[i];
}
DEVFN void stf(void* p, size_t i, float v, bool f32) {
    if (f32) ((float*)p)[i] = v;
    else     ((__hip_bfloat16*)p)[i] = __float2bfloat16(v);
}
DEVFN float lky(float v) { return v > 0.f ? v : 0.2f * v; }

// raw-bits bf16 <-> f32 (no class dependency)
DEVFN float bfbits2f(short s) {
    return __uint_as_float(((unsigned)(unsigned short)s) << 16);
}
DEVFN short f2bfbits(float f) {  // RNE, finite inputs
    unsigned u = __float_as_uint(f);
    return (short)((u + 0x7fffu + ((u >> 16) & 1u)) >> 16);
}

__global__ void detect_k(const void* x, const void* ei, int* flags) {
    if (threadIdx.x == 0 && blockIdx.x == 0) {
        const __hip_bfloat16* xb = (const __hip_bfloat16*)x;
        int bad = 0;
        for (int i = 0; i < 512; ++i) {
            float v = __bfloat162float(xb[i]);
            if (!(v == v) || fabsf(v) > 1.0e6f) bad++;
        }
        flags[0] = (bad > 16) ? 1 : 0;
        const unsigned* w = (const unsigned*)ei;
        int zeros = 0;
        for (int i = 0; i < 64; ++i) if (w[2 * i + 1] == 0u) zeros++;
        flags[1] = (zeros >= 60) ? 1 : 0;
    }
}

__global__ void zero_i32(int* __restrict__ p, int n) {
    int i = blockIdx.x * blockDim.x + threadIdx.x;
    int st = gridDim.x * blockDim.x;
    for (; i < n; i += st) p[i] = 0;
}
__global__ void zero_f32(float* __restrict__ p, long n) {
    long i = (long)blockIdx.x * blockDim.x + threadIdx.x;
    long st = (long)gridDim.x * blockDim.x;
    for (; i < n; i += st) p[i] = 0.f;
}

// ---------------- CSR build (dst-sorted) ----------------
__global__ void hist_k(const void* __restrict__ ei, int E, int* __restrict__ cnt,
                       const int* __restrict__ flags) {
    const bool i64 = flags[1] != 0;
    int e = blockIdx.x * blockDim.x + threadIdx.x;
    if (e >= E) return;
    atomicAdd(&cnt[ldidx(ei, (size_t)E + e, i64)], 1);
}

__global__ void scan_block_k(const int* __restrict__ cnt, int* __restrict__ incl,
                             int* __restrict__ part, int N) {
    __shared__ int sm[256];
    int tid = threadIdx.x;
    int i = blockIdx.x * 256 + tid;
    int v = (i < N) ? cnt[i] : 0;
    sm[tid] = v;
    __syncthreads();
    for (int o = 1; o < 256; o <<= 1) {
        int t = (tid >= o) ? sm[tid - o] : 0;
        __syncthreads();
        sm[tid] += t;
        __syncthreads();
    }
    if (i < N) incl[i] = sm[tid];
    if (tid == 255) part[blockIdx.x] = sm[255];
}

__global__ void scan_part_k(int* __restrict__ part, int nb) {
    __shared__ int sm[256];
    __shared__ int off;
    int tid = threadIdx.x;
    if (tid == 0) off = 0;
    __syncthreads();
    for (int b = 0; b < nb; b += 256) {
        int i = b + tid;
        int v = (i < nb) ? part[i] : 0;
        sm[tid] = v;
        __syncthreads();
        for (int o = 1; o < 256; o <<= 1) {
            int t = (tid >= o) ? sm[tid - o] : 0;
            __syncthreads();
            sm[tid] += t;
            __syncthreads();
        }
        if (i < nb) part[i] = sm[tid] - v + off;
        __syncthreads();
        if (tid == 255) off += sm[255];
        __syncthreads();
    }
}

__global__ void finalize_scan_k(int* __restrict__ incl_cur, const int* __restrict__ cnt,
                                const int* __restrict__ part, int* __restrict__ rs,
                                int N, int E) {
    int i = blockIdx.x * 256 + threadIdx.x;
    if (i >= N) return;
    int v = incl_cur[i] - cnt[i] + part[blockIdx.x];
    rs[i] = v;
    incl_cur[i] = v;
    if (i == N - 1) rs[N] = E;
}

__global__ void scatter_csr_k(const void* __restrict__ ei, int E, int* __restrict__ cur,
                              int* __restrict__ csr_src, int* __restrict__ csr_eid,
                              const int* __restrict__ flags) {
    const bool i64 = flags[1] != 0;
    int e = blockIdx.x * blockDim.x + threadIdx.x;
    if (e >= E) return;
    int s = ldidx(ei, e, i64);
    int d = ldidx(ei, (size_t)E + e, i64);
    int p = atomicAdd(&cur[d], 1);
    csr_src[p] = s;
    csr_eid[p] = e;
}

// ---------------- MFMA GEMM: h = A @ W, fused alpha dots ----------------
// Block: 256 thr = 4 waves; wave handles 16 nodes x FOUT cols.
// Wt staged in LDS as [FOUT][128] bf16, XOR-swizzled (kbyte ^= (col&7)<<4).
template <int DSRC, int FOUT, int HEADS>
__global__ __launch_bounds__(256) void gemm_alpha_mfma_k(
    const void* __restrict__ xin, const void* __restrict__ Wv,
    const void* __restrict__ asv, const void* __restrict__ adv,
    short* __restrict__ h_bf, float* __restrict__ as_out, float* __restrict__ ad_out,
    int N, const int* __restrict__ flags)
{
    constexpr int FIN = 128;
    constexpr int NCT = FOUT / 16;      // col-tiles
    constexpr int CPH = FOUT / HEADS;   // cols per head
    constexpr int CTPH = CPH / 16;      // col-tiles per head
    const bool f32 = flags[0] != 0;

    __shared__ short Wt[FOUT * FIN];    // swizzled, col-major

    for (int i = threadIdx.x; i < FIN * FOUT; i += 256) {
        int k = i / FOUT, c = i - (i / FOUT) * FOUT;
        short w;
        if (DSRC == 0 && f32) w = f2bfbits(((const float*)Wv)[i]);
        else if (f32)         w = f2bfbits(((const float*)Wv)[i]);
        else                  w = ((const short*)Wv)[i];
        *(short*)((char*)Wt + (size_t)c * (FIN * 2) + (((k * 2) ^ ((c & 7) << 4)))) = w;
    }
    __syncthreads();

    const int wv = threadIdx.x >> 6;
    const int lane = threadIdx.x & 63;
    const int m0 = blockIdx.x * 64 + wv * 16;
    if (m0 >= N) return;
    const int lrow = lane & 15;   // A row / C-D col
    const int lk   = lane >> 4;   // k-group / C-D row-group

    // A fragments for 4 k-steps: lane holds A[row=lrow][k = ks*32 + lk*8 + j]
    short8 afrag[4];
    if (DSRC == 0 && f32) {
        const float* xf = (const float*)xin + (size_t)(m0 + lrow) * FIN + lk * 8;
#pragma unroll
        for (int ks = 0; ks < 4; ++ks) {
            short8 t;
#pragma unroll
            for (int j = 0; j < 8; ++j) t[j] = f2bfbits(xf[ks * 32 + j]);
            afrag[ks] = t;
        }
    } else {
        const short* xb = (const short*)xin + (size_t)(m0 + lrow) * FIN + lk * 8;
#pragma unroll
        for (int ks = 0; ks < 4; ++ks)
            afrag[ks] = *(const short8*)(xb + ks * 32);
    }

    float csA[HEADS][4], cdA[HEADS][4];
#pragma unroll
    for (int hd = 0; hd < HEADS; ++hd)
#pragma unroll
        for (int r = 0; r < 4; ++r) { csA[hd][r] = 0.f; cdA[hd][r] = 0.f; }

#pragma unroll
    for (int ct = 0; ct < NCT; ++ct) {
        const int col = ct * 16 + lrow;
        const int hd = ct / CTPH;
        f32x4 acc = {0.f, 0.f, 0.f, 0.f};
#pragma unroll
        for (int ks = 0; ks < 4; ++ks) {
            const int kbyte = ks * 64 + lk * 16;
            short8 bfrag = *(const short8*)((const char*)Wt +
                               (size_t)col * (FIN * 2) + (kbyte ^ ((col & 7) << 4)));
            acc = __builtin_amdgcn_mfma_f32_16x16x32_bf16(afrag[ks], bfrag, acc, 0, 0, 0);
        }
        const float asc = ldf(asv, col, f32);
        const float adc = ldf(adv, col, f32);
#pragma unroll
        for (int r = 0; r < 4; ++r) {
            h_bf[(size_t)(m0 + lk * 4 + r) * FOUT + col] = f2bfbits(acc[r]);
            csA[hd][r] += acc[r] * asc;
            cdA[hd][r] += acc[r] * adc;
        }
    }

    // reduce dots across the 16 lanes of each row-group
#pragma unroll
    for (int hd = 0; hd < HEADS; ++hd)
#pragma unroll
        for (int r = 0; r < 4; ++r) {
            float cs = csA[hd][r], cd = cdA[hd][r];
            for (int o = 1; o < 16; o <<= 1) {
                cs += __shfl_xor(cs, o);
                cd += __shfl_xor(cd, o);
            }
            csA[hd][r] = cs; cdA[hd][r] = cd;
        }
    if (lrow == 0) {
#pragma unroll
        for (int r = 0; r < 4; ++r) {
            int n = m0 + lk * 4 + r;
#pragma unroll
            for (int hd = 0; hd < HEADS; ++hd) {
                as_out[(size_t)n * HEADS + hd] = csA[hd][r];
                ad_out[(size_t)n * HEADS + hd] = cdA[hd][r];
            }
        }
    }
}

// ---------------- fused per-node segment softmax over CSR ----------------
template <int HEADS>
__global__ __launch_bounds__(256) void softmax_csr_k(
    const float* __restrict__ as_, const float* __restrict__ ad_,
    const int* __restrict__ rs, const int* __restrict__ csr_src, const int* __restrict__ csr_eid,
    float* __restrict__ alpha_csr, void* __restrict__ dout, size_t aoff,
    int N, const int* __restrict__ flags)
{
    const bool f32 = flags[0] != 0;
    const int wid = (blockIdx.x * 256 + threadIdx.x) >> 6;
    const int lane = threadIdx.x & 63;
    if (wid >= N) return;
    const int beg = rs[wid], end = rs[wid + 1];

    const float ad0 = ad_[(size_t)wid * HEADS];
    const float ad1 = (HEADS == 2) ? ad_[(size_t)wid * HEADS + 1] : 0.f;

    float m0 = -1e30f, m1 = -1e30f;
    for (int p = beg + lane; p < end; p += 64) {
        int s = csr_src[p];
        m0 = fmaxf(m0, lky(as_[(size_t)s * HEADS] + ad0));
        if (HEADS == 2) m1 = fmaxf(m1, lky(as_[(size_t)s * HEADS + 1] + ad1));
    }
    for (int o = 1; o < 64; o <<= 1) {
        m0 = fmaxf(m0, __shfl_xor(m0, o));
        if (HEADS == 2) m1 = fmaxf(m1, __shfl_xor(m1, o));
    }
    float s0 = 0.f, s1 = 0.f;
    for (int p = beg + lane; p < end; p += 64) {
        int s = csr_src[p];
        s0 += expf(lky(as_[(size_t)s * HEADS] + ad0) - m0);
        if (HEADS == 2) s1 += expf(lky(as_[(size_t)s * HEADS + 1] + ad1) - m1);
    }
    for (int o = 1; o < 64; o <<= 1) {
        s0 += __shfl_xor(s0, o);
        if (HEADS == 2) s1 += __shfl_xor(s1, o);
    }
    const float inv0 = 1.f / (s0 + 1e-16f);
    const float inv1 = 1.f / (s1 + 1e-16f);

    for (int p = beg + lane; p < end; p += 64) {
        int s = csr_src[p];
        int eid = csr_eid[p];
        float a0 = expf(lky(as_[(size_t)s * HEADS] + ad0) - m0) * inv0;
        alpha_csr[(size_t)p * HEADS] = a0;
        stf(dout, aoff + (size_t)eid * HEADS, a0, f32);
        if (HEADS == 2) {
            float a1 = expf(lky(as_[(size_t)s * HEADS + 1] + ad1) - m1) * inv1;
            alpha_csr[(size_t)p * 2 + 1] = a1;
            stf(dout, aoff + (size_t)eid * 2 + 1, a1, f32);
        }
    }
}

// ---------------- CSR pull message-sum, bf16 h, FOUT=128 ----------------
template <int HEADS, bool RELU>
__global__ __launch_bounds__(128) void pull128_bf_k(
    const short* __restrict__ h_bf, const float* __restrict__ alpha_csr,
    const int* __restrict__ rs, const int* __restrict__ csr_src,
    const void* __restrict__ bias, short* __restrict__ z_bf,
    int N, const int* __restrict__ flags)
{
    const bool f32 = flags[0] != 0;
    const int d = blockIdx.x;
    const int col = threadIdx.x;
    const int h = (HEADS == 2) ? (col >> 6) : 0;
    const int beg = rs[d], end = rs[d + 1];
    float acc = 0.f;
    for (int p = beg; p < end; ++p) {
        int sj = csr_src[p];
        float a = alpha_csr[(size_t)p * HEADS + h];
        acc = fmaf(bfbits2f(h_bf[(size_t)sj * 128 + col]), a, acc);
    }
    float v = acc + ldf(bias, col, f32);
    if (RELU) v = fmaxf(v, 0.f);
    z_bf[(size_t)d * 128 + col] = f2bfbits(v);
}

// ---------------- CSR pull, bf16 h, FOUT=16 (8 nodes/block) ----------------
__global__ __launch_bounds__(128) void pull16_bf_k(
    const short* __restrict__ h_bf, const float* __restrict__ alpha_csr,
    const int* __restrict__ rs, const int* __restrict__ csr_src,
    float* __restrict__ out, int N)
{
    const int g = threadIdx.x >> 4;
    const int c = threadIdx.x & 15;
    const int d = blockIdx.x * 8 + g;
    if (d >= N) return;
    const int beg = rs[d], end = rs[d + 1];
    float acc = 0.f;
    for (int p = beg; p < end; ++p)
        acc = fmaf(bfbits2f(h_bf[(size_t)csr_src[p] * 16 + c]), alpha_csr[p], acc);
    out[(size_t)d * 16 + c] = acc;
}

// layer3 finalize: emb = acc + b3, write emb to d_out, pool per-graph sums
__global__ __launch_bounds__(256) void finalize3_k(
    const float* __restrict__ acc, const void* __restrict__ bias,
    const void* __restrict__ batch, void* __restrict__ dout, size_t emb_off,
    float* __restrict__ g_sum, int N, const int* __restrict__ flags)
{
    const bool f32 = flags[0] != 0;
    const bool i64 = flags[1] != 0;
    __shared__ float gp[256];
    int tid = threadIdx.x;
    gp[tid] = 0.f;
    __syncthreads();
    long idx = (long)blockIdx.x * 256 + tid;
    if (idx < (long)N * 16) {
        int n = (int)(idx >> 4), col = (int)(idx & 15);
        float v = acc[idx] + ldf(bias, col, f32);
        stf(dout, emb_off + idx, v, f32);
        int g = ldidx(batch, n, i64);
        atomicAdd(&gp[g * 16 + col], v);
    }
    __syncthreads();
    float pv = gp[tid];
    if (pv != 0.f) atomicAdd(&g_sum[tid], pv);
}

__global__ __launch_bounds__(256) void head_k(
    const float* __restrict__ g_sum, const void* __restrict__ batch,
    const void* __restrict__ Wl, const void* __restrict__ bl,
    void* __restrict__ dout, size_t gemb_off, int N, const int* __restrict__ flags)
{
    const bool f32 = flags[0] != 0;
    const bool i64 = flags[1] != 0;
    __shared__ float ge[256];
    __shared__ int cnts[16];
    int tid = threadIdx.x;
    if (tid < 16) {
        int lo = 0, hi = N;
        while (lo < hi) { int mid = (lo + hi) >> 1; if (ldidx(batch, mid, i64) < tid) lo = mid + 1; else hi = mid; }
        int l2 = 0, h2 = N;
        while (l2 < h2) { int mid = (l2 + h2) >> 1; if (ldidx(batch, mid, i64) <= tid) l2 = mid + 1; else h2 = mid; }
        cnts[tid] = l2 - lo;
    }
    __syncthreads();
    {
        int g = tid >> 4;
        float v = g_sum[tid] / fmaxf((float)cnts[g], 1.f);
        ge[tid] = v;
        stf(dout, gemb_off + tid, v, f32);
    }
    __syncthreads();
    if (tid < 32) {
        int g = tid >> 1, j = tid & 1;
        float s = ldf(bl, j, f32);
        for (int c = 0; c < 16; ++c) s += ge[g * 16 + c] * ldf(Wl, (size_t)c * 2 + j, f32);
        stf(dout, (size_t)g * 2 + j, s, f32);
    }
}

static inline int cdiv(long a, int b) { return (int)((a + b - 1) / b); }

extern "C" void kernel_launch(void* const* d_in, const int* in_sizes, int n_in,
                              void* d_out, int out_size, void* d_ws, size_t ws_size,
                              hipStream_t stream)
{
    const void* x   = d_in[0];
    const void* ei  = d_in[1];
    const void* batch = d_in[2];
    const void* W1  = d_in[3];
    const void* as1 = d_in[4];
    const void* ad1 = d_in[5];
    const void* b1  = d_in[6];
    const void* W2  = d_in[7];
    const void* as2 = d_in[8];
    const void* ad2 = d_in[9];
    const void* b2  = d_in[10];
    const void* W3  = d_in[11];
    const void* as3 = d_in[12];
    const void* ad3 = d_in[13];
    const void* b3  = d_in[14];
    const void* Wl  = d_in[15];
    const void* bl  = d_in[16];

    const int N = in_sizes[0] / 128;
    const int E = in_sizes[1] / 2;

    int* flags = (int*)d_ws;
    float* ws = (float*)d_ws + 16;
    size_t o = 0;
    float* as_  = ws + o; o += (size_t)N * 2;
    float* ad_  = ws + o; o += (size_t)N * 2;
    float* alpha_csr = ws + o; o += (size_t)E * 2;
    float* bufE = ws + o; o += (size_t)N * 16;
    float* g_sum = ws + o; o += 256;
    short* hX = (short*)(ws + o); o += (size_t)N * 64;  // h (bf16), gemm out
    short* hZ = (short*)(ws + o); o += (size_t)N * 64;  // z (bf16), pull out
    short* h3 = (short*)(ws + o); o += (size_t)N * 8;   // layer3 h (bf16)
    int* ip = (int*)(ws + o);
    int* cnt  = ip;            ip += N;
    int* incl = ip;            ip += N;   // reused as `cur` after finalize_scan
    int* part = ip;            ip += 256;
    int* rs   = ip;            ip += N + 1;
    int* csr_src = ip;         ip += E;
    int* csr_eid = ip;         ip += E;

    const size_t off_gemb = 32;
    const size_t off_emb  = 32 + 256;
    const size_t off_a1   = off_emb + (size_t)N * 16;
    const size_t off_a2   = off_a1 + (size_t)E * 2;
    const size_t off_a3   = off_a2 + (size_t)E;

    const int B = 256;
    const int nbN = cdiv(N, 256);
    const int gemmBlocks = cdiv(N, 64);

    detect_k<<<1, 64, 0, stream>>>(x, ei, flags);

    // ---- CSR build (dst-sorted src + edge ids), reused by all layers ----
    zero_i32<<<nbN, B, 0, stream>>>(cnt, N);
    hist_k<<<cdiv(E, B), B, 0, stream>>>(ei, E, cnt, flags);
    scan_block_k<<<nbN, B, 0, stream>>>(cnt, incl, part, N);
    scan_part_k<<<1, B, 0, stream>>>(part, nbN);
    finalize_scan_k<<<nbN, B, 0, stream>>>(incl, cnt, part, rs, N, E);
    scatter_csr_k<<<cdiv(E, B), B, 0, stream>>>(ei, E, incl, csr_src, csr_eid, flags);

    // ---------------- Layer 1: 128 -> (2 heads x 64), concat, relu ----------------
    gemm_alpha_mfma_k<0, 128, 2><<<gemmBlocks, 256, 0, stream>>>(x, W1, as1, ad1, hX, as_, ad_, N, flags);
    softmax_csr_k<2><<<cdiv(N, 4), 256, 0, stream>>>(as_, ad_, rs, csr_src, csr_eid,
                                                     alpha_csr, d_out, off_a1, N, flags);
    pull128_bf_k<2, true><<<N, 128, 0, stream>>>(hX, alpha_csr, rs, csr_src, b1, hZ, N, flags);

    // ---------------- Layer 2: 128 -> 128, 1 head, mean(=identity), relu ----------------
    gemm_alpha_mfma_k<1, 128, 1><<<gemmBlocks, 256, 0, stream>>>(hZ, W2, as2, ad2, hX, as_, ad_, N, flags);
    softmax_csr_k<1><<<cdiv(N, 4), 256, 0, stream>>>(as_, ad_, rs, csr_src, csr_eid,
                                                     alpha_csr, d_out, off_a2, N, flags);
    pull128_bf_k<1, true><<<N, 128, 0, stream>>>(hX, alpha_csr, rs, csr_src, b2, hZ, N, flags);

    // ---------------- Layer 3: 128 -> 16, 1 head, mean(=identity), no relu ----------------
    gemm_alpha_mfma_k<1, 16, 1><<<gemmBlocks, 256, 0, stream>>>(hZ, W3, as3, ad3, h3, as_, ad_, N, flags);
    softmax_csr_k<1><<<cdiv(N, 4), 256, 0, stream>>>(as_, ad_, rs, csr_src, csr_eid,
                                                     alpha_csr, d_out, off_a3, N, flags);
    pull16_bf_k<<<cdiv(N, 8), 128, 0, stream>>>(h3, alpha_csr, rs, csr_src, bufE, N);
    zero_f32<<<1, B, 0, stream>>>(g_sum, 256);
    finalize3_k<<<cdiv((long)N * 16, B), B, 0, stream>>>(bufE, b3, batch, d_out, off_emb, g_sum, N, flags);

    // ---------------- Pool + classifier head ----------------
    head_k<<<1, B, 0, stream>>>(g_sum, batch, Wl, bl, d_out, off_gemb, N, flags);
}

// Round 7
// 390.307 us; speedup vs baseline: 3.7796x; 1.2412x over previous
//
#include <hip/hip_runtime.h>
#include <hip/hip_bf16.h>

#define DEVFN __device__ __forceinline__

using short8 = __attribute__((ext_vector_type(8))) short;
using f32x4  = __attribute__((ext_vector_type(4))) float;

// ---- dual-dtype helpers: flags[0]=1 -> floats are f32 (else bf16);
//                          flags[1]=1 -> ints are int64 (else int32)
DEVFN float ldf(const void* p, size_t i, bool f32) {
    return f32 ? ((const float*)p)[i]
               : __bfloat162float(((const __hip_bfloat16*)p)[i]);
}
DEVFN int ldidx(const void* p, size_t i, bool i64) {
    return i64 ? (int)((const long long*)p)[i] : ((const int*)p)[i];
}
DEVFN void stf(void* p, size_t i, float v, bool f32) {
    if (f32) ((float*)p)[i] = v;
    else     ((__hip_bfloat16*)p)[i] = __float2bfloat16(v);
}
DEVFN float lky(float v) { return v > 0.f ? v : 0.2f * v; }

// raw-bits bf16 <-> f32
DEVFN float bfbits2f(short s) {
    return __uint_as_float(((unsigned)(unsigned short)s) << 16);
}
DEVFN short f2bfbits(float f) {  // RNE, finite inputs
    unsigned u = __float_as_uint(f);
    return (short)((u + 0x7fffu + ((u >> 16) & 1u)) >> 16);
}

__global__ void detect_k(const void* x, const void* ei, int* flags) {
    if (threadIdx.x == 0 && blockIdx.x == 0) {
        const __hip_bfloat16* xb = (const __hip_bfloat16*)x;
        int bad = 0;
        for (int i = 0; i < 512; ++i) {
            float v = __bfloat162float(xb[i]);
            if (!(v == v) || fabsf(v) > 1.0e6f) bad++;
        }
        flags[0] = (bad > 16) ? 1 : 0;
        const unsigned* w = (const unsigned*)ei;
        int zeros = 0;
        for (int i = 0; i < 64; ++i) if (w[2 * i + 1] == 0u) zeros++;
        flags[1] = (zeros >= 60) ? 1 : 0;
    }
}

__global__ void zero_i32(int* __restrict__ p, int n) {
    int i = blockIdx.x * blockDim.x + threadIdx.x;
    int st = gridDim.x * blockDim.x;
    for (; i < n; i += st) p[i] = 0;
}
__global__ void zero_f32(float* __restrict__ p, long n) {
    long i = (long)blockIdx.x * blockDim.x + threadIdx.x;
    long st = (long)gridDim.x * blockDim.x;
    for (; i < n; i += st) p[i] = 0.f;
}

// ---------------- CSR build (dst-sorted) ----------------
__global__ void hist_k(const void* __restrict__ ei, int E, int* __restrict__ cnt,
                       const int* __restrict__ flags) {
    const bool i64 = flags[1] != 0;
    int e = blockIdx.x * blockDim.x + threadIdx.x;
    if (e >= E) return;
    atomicAdd(&cnt[ldidx(ei, (size_t)E + e, i64)], 1);
}

__global__ void scan_block_k(const int* __restrict__ cnt, int* __restrict__ incl,
                             int* __restrict__ part, int N) {
    __shared__ int sm[256];
    int tid = threadIdx.x;
    int i = blockIdx.x * 256 + tid;
    int v = (i < N) ? cnt[i] : 0;
    sm[tid] = v;
    __syncthreads();
    for (int o = 1; o < 256; o <<= 1) {
        int t = (tid >= o) ? sm[tid - o] : 0;
        __syncthreads();
        sm[tid] += t;
        __syncthreads();
    }
    if (i < N) incl[i] = sm[tid];
    if (tid == 255) part[blockIdx.x] = sm[255];
}

__global__ void scan_part_k(int* __restrict__ part, int nb) {
    __shared__ int sm[256];
    __shared__ int off;
    int tid = threadIdx.x;
    if (tid == 0) off = 0;
    __syncthreads();
    for (int b = 0; b < nb; b += 256) {
        int i = b + tid;
        int v = (i < nb) ? part[i] : 0;
        sm[tid] = v;
        __syncthreads();
        for (int o = 1; o < 256; o <<= 1) {
            int t = (tid >= o) ? sm[tid - o] : 0;
            __syncthreads();
            sm[tid] += t;
            __syncthreads();
        }
        if (i < nb) part[i] = sm[tid] - v + off;
        __syncthreads();
        if (tid == 255) off += sm[255];
        __syncthreads();
    }
}

__global__ void finalize_scan_k(int* __restrict__ incl_cur, const int* __restrict__ cnt,
                                const int* __restrict__ part, int* __restrict__ rs,
                                int N, int E) {
    int i = blockIdx.x * 256 + threadIdx.x;
    if (i >= N) return;
    int v = incl_cur[i] - cnt[i] + part[blockIdx.x];
    rs[i] = v;
    incl_cur[i] = v;
    if (i == N - 1) rs[N] = E;
}

__global__ void scatter_csr_k(const void* __restrict__ ei, int E, int* __restrict__ cur,
                              int* __restrict__ csr_src, int* __restrict__ csr_eid,
                              const int* __restrict__ flags) {
    const bool i64 = flags[1] != 0;
    int e = blockIdx.x * blockDim.x + threadIdx.x;
    if (e >= E) return;
    int s = ldidx(ei, e, i64);
    int d = ldidx(ei, (size_t)E + e, i64);
    int p = atomicAdd(&cur[d], 1);
    csr_src[p] = s;
    csr_eid[p] = e;
}

// ---------------- MFMA GEMM: h = A @ W, fused alpha dots (verbatim round 6) ----------------
template <int DSRC, int FOUT, int HEADS>
__global__ __launch_bounds__(256) void gemm_alpha_mfma_k(
    const void* __restrict__ xin, const void* __restrict__ Wv,
    const void* __restrict__ asv, const void* __restrict__ adv,
    short* __restrict__ h_bf, float* __restrict__ as_out, float* __restrict__ ad_out,
    int N, const int* __restrict__ flags)
{
    constexpr int FIN = 128;
    constexpr int NCT = FOUT / 16;
    constexpr int CPH = FOUT / HEADS;
    constexpr int CTPH = CPH / 16;
    const bool f32 = flags[0] != 0;

    __shared__ short Wt[FOUT * FIN];    // swizzled, col-major

    for (int i = threadIdx.x; i < FIN * FOUT; i += 256) {
        int k = i / FOUT, c = i - (i / FOUT) * FOUT;
        short w;
        if (f32) w = f2bfbits(((const float*)Wv)[i]);
        else     w = ((const short*)Wv)[i];
        *(short*)((char*)Wt + (size_t)c * (FIN * 2) + (((k * 2) ^ ((c & 7) << 4)))) = w;
    }
    __syncthreads();

    const int wv = threadIdx.x >> 6;
    const int lane = threadIdx.x & 63;
    const int m0 = blockIdx.x * 64 + wv * 16;
    if (m0 >= N) return;
    const int lrow = lane & 15;
    const int lk   = lane >> 4;

    short8 afrag[4];
    if (DSRC == 0 && f32) {
        const float* xf = (const float*)xin + (size_t)(m0 + lrow) * FIN + lk * 8;
#pragma unroll
        for (int ks = 0; ks < 4; ++ks) {
            short8 t;
#pragma unroll
            for (int j = 0; j < 8; ++j) t[j] = f2bfbits(xf[ks * 32 + j]);
            afrag[ks] = t;
        }
    } else {
        const short* xb = (const short*)xin + (size_t)(m0 + lrow) * FIN + lk * 8;
#pragma unroll
        for (int ks = 0; ks < 4; ++ks)
            afrag[ks] = *(const short8*)(xb + ks * 32);
    }

    float csA[HEADS][4], cdA[HEADS][4];
#pragma unroll
    for (int hd = 0; hd < HEADS; ++hd)
#pragma unroll
        for (int r = 0; r < 4; ++r) { csA[hd][r] = 0.f; cdA[hd][r] = 0.f; }

#pragma unroll
    for (int ct = 0; ct < NCT; ++ct) {
        const int col = ct * 16 + lrow;
        const int hd = ct / CTPH;
        f32x4 acc = {0.f, 0.f, 0.f, 0.f};
#pragma unroll
        for (int ks = 0; ks < 4; ++ks) {
            const int kbyte = ks * 64 + lk * 16;
            short8 bfrag = *(const short8*)((const char*)Wt +
                               (size_t)col * (FIN * 2) + (kbyte ^ ((col & 7) << 4)));
            acc = __builtin_amdgcn_mfma_f32_16x16x32_bf16(afrag[ks], bfrag, acc, 0, 0, 0);
        }
        const float asc = ldf(asv, col, f32);
        const float adc = ldf(adv, col, f32);
#pragma unroll
        for (int r = 0; r < 4; ++r) {
            h_bf[(size_t)(m0 + lk * 4 + r) * FOUT + col] = f2bfbits(acc[r]);
            csA[hd][r] += acc[r] * asc;
            cdA[hd][r] += acc[r] * adc;
        }
    }

#pragma unroll
    for (int hd = 0; hd < HEADS; ++hd)
#pragma unroll
        for (int r = 0; r < 4; ++r) {
            float cs = csA[hd][r], cd = cdA[hd][r];
            for (int o = 1; o < 16; o <<= 1) {
                cs += __shfl_xor(cs, o);
                cd += __shfl_xor(cd, o);
            }
            csA[hd][r] = cs; cdA[hd][r] = cd;
        }
    if (lrow == 0) {
#pragma unroll
        for (int r = 0; r < 4; ++r) {
            int n = m0 + lk * 4 + r;
#pragma unroll
            for (int hd = 0; hd < HEADS; ++hd) {
                as_out[(size_t)n * HEADS + hd] = csA[hd][r];
                ad_out[(size_t)n * HEADS + hd] = cdA[hd][r];
            }
        }
    }
}

// ---------------- fused per-node segment softmax over CSR (verbatim round 5/6) ----------------
template <int HEADS>
__global__ __launch_bounds__(256) void softmax_csr_k(
    const float* __restrict__ as_, const float* __restrict__ ad_,
    const int* __restrict__ rs, const int* __restrict__ csr_src, const int* __restrict__ csr_eid,
    float* __restrict__ alpha_csr, void* __restrict__ dout, size_t aoff,
    int N, const int* __restrict__ flags)
{
    const bool f32 = flags[0] != 0;
    const int wid = (blockIdx.x * 256 + threadIdx.x) >> 6;
    const int lane = threadIdx.x & 63;
    if (wid >= N) return;
    const int beg = rs[wid], end = rs[wid + 1];

    const float ad0 = ad_[(size_t)wid * HEADS];
    const float ad1 = (HEADS == 2) ? ad_[(size_t)wid * HEADS + 1] : 0.f;

    float m0 = -1e30f, m1 = -1e30f;
    for (int p = beg + lane; p < end; p += 64) {
        int s = csr_src[p];
        m0 = fmaxf(m0, lky(as_[(size_t)s * HEADS] + ad0));
        if (HEADS == 2) m1 = fmaxf(m1, lky(as_[(size_t)s * HEADS + 1] + ad1));
    }
    for (int o = 1; o < 64; o <<= 1) {
        m0 = fmaxf(m0, __shfl_xor(m0, o));
        if (HEADS == 2) m1 = fmaxf(m1, __shfl_xor(m1, o));
    }
    float s0 = 0.f, s1 = 0.f;
    for (int p = beg + lane; p < end; p += 64) {
        int s = csr_src[p];
        s0 += expf(lky(as_[(size_t)s * HEADS] + ad0) - m0);
        if (HEADS == 2) s1 += expf(lky(as_[(size_t)s * HEADS + 1] + ad1) - m1);
    }
    for (int o = 1; o < 64; o <<= 1) {
        s0 += __shfl_xor(s0, o);
        if (HEADS == 2) s1 += __shfl_xor(s1, o);
    }
    const float inv0 = 1.f / (s0 + 1e-16f);
    const float inv1 = 1.f / (s1 + 1e-16f);

    for (int p = beg + lane; p < end; p += 64) {
        int s = csr_src[p];
        int eid = csr_eid[p];
        float a0 = expf(lky(as_[(size_t)s * HEADS] + ad0) - m0) * inv0;
        alpha_csr[(size_t)p * HEADS] = a0;
        stf(dout, aoff + (size_t)eid * HEADS, a0, f32);
        if (HEADS == 2) {
            float a1 = expf(lky(as_[(size_t)s * HEADS + 1] + ad1) - m1) * inv1;
            alpha_csr[(size_t)p * 2 + 1] = a1;
            stf(dout, aoff + (size_t)eid * 2 + 1, a1, f32);
        }
    }
}

// ---------------- CSR pull v2, FOUT=128: wave/node, 4 edges x 16B lanes ----------------
template <int HEADS, bool RELU>
__global__ __launch_bounds__(256) void pull128_v2_k(
    const short* __restrict__ h_bf, const float* __restrict__ alpha_csr,
    const int* __restrict__ rs, const int* __restrict__ csr_src,
    const void* __restrict__ bias, short* __restrict__ z_bf,
    int N, const int* __restrict__ flags)
{
    const bool f32 = flags[0] != 0;
    const int wid = (blockIdx.x * 256 + threadIdx.x) >> 6;
    if (wid >= N) return;
    const int lane = threadIdx.x & 63;
    const int cg = lane & 15;     // col-group: cols cg*8 .. cg*8+7
    const int es = lane >> 4;     // edge slot 0..3
    const int h = (HEADS == 2) ? (cg >> 3) : 0;   // cg<8 -> head0
    const int beg = rs[wid], end = rs[wid + 1];

    float acc[8] = {0.f, 0.f, 0.f, 0.f, 0.f, 0.f, 0.f, 0.f};
    for (int base = beg; base < end; base += 4) {
        const int p = base + es;
        if (p < end) {
            const int sj = csr_src[p];
            const float a = alpha_csr[(size_t)p * HEADS + h];
            const short8 hv = *(const short8*)(h_bf + (size_t)sj * 128 + cg * 8);
#pragma unroll
            for (int j = 0; j < 8; ++j)
                acc[j] = fmaf(bfbits2f(hv[j]), a, acc[j]);
        }
    }
#pragma unroll
    for (int j = 0; j < 8; ++j) {
        acc[j] += __shfl_xor(acc[j], 16);
        acc[j] += __shfl_xor(acc[j], 32);
    }
    if (es == 0) {
        short8 outv;
#pragma unroll
        for (int j = 0; j < 8; ++j) {
            float v = acc[j] + ldf(bias, cg * 8 + j, f32);
            if (RELU) v = fmaxf(v, 0.f);
            outv[j] = f2bfbits(v);
        }
        *(short8*)(z_bf + (size_t)wid * 128 + cg * 8) = outv;
    }
}

// ---------------- CSR pull v2, FOUT=16: wave/node, 8 edges x 4B lanes ----------------
__global__ __launch_bounds__(256) void pull16_v2_k(
    const short* __restrict__ h_bf, const float* __restrict__ alpha_csr,
    const int* __restrict__ rs, const int* __restrict__ csr_src,
    float* __restrict__ out, int N)
{
    const int wid = (blockIdx.x * 256 + threadIdx.x) >> 6;
    if (wid >= N) return;
    const int lane = threadIdx.x & 63;
    const int cg = lane & 7;      // cols cg*2, cg*2+1
    const int es = lane >> 3;     // edge slot 0..7
    const int beg = rs[wid], end = rs[wid + 1];

    float a0 = 0.f, a1 = 0.f;
    for (int base = beg; base < end; base += 8) {
        const int p = base + es;
        if (p < end) {
            const int sj = csr_src[p];
            const float a = alpha_csr[p];
            const int hv = *(const int*)(h_bf + (size_t)sj * 16 + cg * 2);
            a0 = fmaf(bfbits2f((short)(hv & 0xffff)), a, a0);
            a1 = fmaf(bfbits2f((short)(hv >> 16)), a, a1);
        }
    }
#pragma unroll
    for (int o = 8; o < 64; o <<= 1) {
        a0 += __shfl_xor(a0, o);
        a1 += __shfl_xor(a1, o);
    }
    if (es == 0) {
        out[(size_t)wid * 16 + cg * 2]     = a0;
        out[(size_t)wid * 16 + cg * 2 + 1] = a1;
    }
}

// layer3 finalize: emb = acc + b3, write emb to d_out, pool per-graph sums
__global__ __launch_bounds__(256) void finalize3_k(
    const float* __restrict__ acc, const void* __restrict__ bias,
    const void* __restrict__ batch, void* __restrict__ dout, size_t emb_off,
    float* __restrict__ g_sum, int N, const int* __restrict__ flags)
{
    const bool f32 = flags[0] != 0;
    const bool i64 = flags[1] != 0;
    __shared__ float gp[256];
    int tid = threadIdx.x;
    gp[tid] = 0.f;
    __syncthreads();
    long idx = (long)blockIdx.x * 256 + tid;
    if (idx < (long)N * 16) {
        int n = (int)(idx >> 4), col = (int)(idx & 15);
        float v = acc[idx] + ldf(bias, col, f32);
        stf(dout, emb_off + idx, v, f32);
        int g = ldidx(batch, n, i64);
        atomicAdd(&gp[g * 16 + col], v);
    }
    __syncthreads();
    float pv = gp[tid];
    if (pv != 0.f) atomicAdd(&g_sum[tid], pv);
}

__global__ __launch_bounds__(256) void head_k(
    const float* __restrict__ g_sum, const void* __restrict__ batch,
    const void* __restrict__ Wl, const void* __restrict__ bl,
    void* __restrict__ dout, size_t gemb_off, int N, const int* __restrict__ flags)
{
    const bool f32 = flags[0] != 0;
    const bool i64 = flags[1] != 0;
    __shared__ float ge[256];
    __shared__ int cnts[16];
    int tid = threadIdx.x;
    if (tid < 16) {
        int lo = 0, hi = N;
        while (lo < hi) { int mid = (lo + hi) >> 1; if (ldidx(batch, mid, i64) < tid) lo = mid + 1; else hi = mid; }
        int l2 = 0, h2 = N;
        while (l2 < h2) { int mid = (l2 + h2) >> 1; if (ldidx(batch, mid, i64) <= tid) l2 = mid + 1; else h2 = mid; }
        cnts[tid] = l2 - lo;
    }
    __syncthreads();
    {
        int g = tid >> 4;
        float v = g_sum[tid] / fmaxf((float)cnts[g], 1.f);
        ge[tid] = v;
        stf(dout, gemb_off + tid, v, f32);
    }
    __syncthreads();
    if (tid < 32) {
        int g = tid >> 1, j = tid & 1;
        float s = ldf(bl, j, f32);
        for (int c = 0; c < 16; ++c) s += ge[g * 16 + c] * ldf(Wl, (size_t)c * 2 + j, f32);
        stf(dout, (size_t)g * 2 + j, s, f32);
    }
}

static inline int cdiv(long a, int b) { return (int)((a + b - 1) / b); }

extern "C" void kernel_launch(void* const* d_in, const int* in_sizes, int n_in,
                              void* d_out, int out_size, void* d_ws, size_t ws_size,
                              hipStream_t stream)
{
    const void* x   = d_in[0];
    const void* ei  = d_in[1];
    const void* batch = d_in[2];
    const void* W1  = d_in[3];
    const void* as1 = d_in[4];
    const void* ad1 = d_in[5];
    const void* b1  = d_in[6];
    const void* W2  = d_in[7];
    const void* as2 = d_in[8];
    const void* ad2 = d_in[9];
    const void* b2  = d_in[10];
    const void* W3  = d_in[11];
    const void* as3 = d_in[12];
    const void* ad3 = d_in[13];
    const void* b3  = d_in[14];
    const void* Wl  = d_in[15];
    const void* bl  = d_in[16];

    const int N = in_sizes[0] / 128;
    const int E = in_sizes[1] / 2;

    int* flags = (int*)d_ws;
    float* ws = (float*)d_ws + 16;
    size_t o = 0;
    float* as_  = ws + o; o += (size_t)N * 2;
    float* ad_  = ws + o; o += (size_t)N * 2;
    float* alpha_csr = ws + o; o += (size_t)E * 2;
    float* bufE = ws + o; o += (size_t)N * 16;
    float* g_sum = ws + o; o += 256;
    short* hX = (short*)(ws + o); o += (size_t)N * 64;  // h (bf16), gemm out
    short* hZ = (short*)(ws + o); o += (size_t)N * 64;  // z (bf16), pull out
    short* h3 = (short*)(ws + o); o += (size_t)N * 8;   // layer3 h (bf16)
    int* ip = (int*)(ws + o);
    int* cnt  = ip;            ip += N;
    int* incl = ip;            ip += N;   // reused as `cur` after finalize_scan
    int* part = ip;            ip += 256;
    int* rs   = ip;            ip += N + 1;
    int* csr_src = ip;         ip += E;
    int* csr_eid = ip;         ip += E;

    const size_t off_gemb = 32;
    const size_t off_emb  = 32 + 256;
    const size_t off_a1   = off_emb + (size_t)N * 16;
    const size_t off_a2   = off_a1 + (size_t)E * 2;
    const size_t off_a3   = off_a2 + (size_t)E;

    const int B = 256;
    const int nbN = cdiv(N, 256);
    const int gemmBlocks = cdiv(N, 64);
    const int waveBlocks = cdiv(N, 4);   // 4 waves (nodes) per 256-thr block

    detect_k<<<1, 64, 0, stream>>>(x, ei, flags);

    // ---- CSR build (dst-sorted src + edge ids), reused by all layers ----
    zero_i32<<<nbN, B, 0, stream>>>(cnt, N);
    hist_k<<<cdiv(E, B), B, 0, stream>>>(ei, E, cnt, flags);
    scan_block_k<<<nbN, B, 0, stream>>>(cnt, incl, part, N);
    scan_part_k<<<1, B, 0, stream>>>(part, nbN);
    finalize_scan_k<<<nbN, B, 0, stream>>>(incl, cnt, part, rs, N, E);
    scatter_csr_k<<<cdiv(E, B), B, 0, stream>>>(ei, E, incl, csr_src, csr_eid, flags);

    // ---------------- Layer 1: 128 -> (2 heads x 64), concat, relu ----------------
    gemm_alpha_mfma_k<0, 128, 2><<<gemmBlocks, 256, 0, stream>>>(x, W1, as1, ad1, hX, as_, ad_, N, flags);
    softmax_csr_k<2><<<waveBlocks, 256, 0, stream>>>(as_, ad_, rs, csr_src, csr_eid,
                                                     alpha_csr, d_out, off_a1, N, flags);
    pull128_v2_k<2, true><<<waveBlocks, 256, 0, stream>>>(hX, alpha_csr, rs, csr_src, b1, hZ, N, flags);

    // ---------------- Layer 2: 128 -> 128, 1 head, mean(=identity), relu ----------------
    gemm_alpha_mfma_k<1, 128, 1><<<gemmBlocks, 256, 0, stream>>>(hZ, W2, as2, ad2, hX, as_, ad_, N, flags);
    softmax_csr_k<1><<<waveBlocks, 256, 0, stream>>>(as_, ad_, rs, csr_src, csr_eid,
                                                     alpha_csr, d_out, off_a2, N, flags);
    pull128_v2_k<1, true><<<waveBlocks, 256, 0, stream>>>(hX, alpha_csr, rs, csr_src, b2, hZ, N, flags);

    // ---------------- Layer 3: 128 -> 16, 1 head, mean(=identity), no relu ----------------
    gemm_alpha_mfma_k<1, 16, 1><<<gemmBlocks, 256, 0, stream>>>(hZ, W3, as3, ad3, h3, as_, ad_, N, flags);
    softmax_csr_k<1><<<waveBlocks, 256, 0, stream>>>(as_, ad_, rs, csr_src, csr_eid,
                                                     alpha_csr, d_out, off_a3, N, flags);
    pull16_v2_k<<<waveBlocks, 256, 0, stream>>>(h3, alpha_csr, rs, csr_src, bufE, N);
    zero_f32<<<1, B, 0, stream>>>(g_sum, 256);
    finalize3_k<<<cdiv((long)N * 16, B), B, 0, stream>>>(bufE, b3, batch, d_out, off_emb, g_sum, N, flags);

    // ---------------- Pool + classifier head ----------------
    head_k<<<1, B, 0, stream>>>(g_sum, batch, Wl, bl, d_out, off_gemb, N, flags);
}